// Round 7
// baseline (1718.512 us; speedup 1.0000x reference)
//
#include <hip/hip_runtime.h>
#include <hip/hip_bf16.h>
#include <math.h>

typedef unsigned short u16;
typedef __attribute__((ext_vector_type(8))) short short8;
typedef __attribute__((ext_vector_type(4))) float f32x4;

__device__ __forceinline__ u16 f2bf(float f) {
  union { float f; unsigned u; } v; v.f = f;
  unsigned r = v.u + 0x7fffu + ((v.u >> 16) & 1u);
  return (u16)(r >> 16);
}

// async global->LDS, 16B/lane. LDS dest is wave-uniform base; HW adds lane*16.
__device__ __forceinline__ void glds16(const u16* g, u16* l) {
  __builtin_amdgcn_global_load_lds(
      (const __attribute__((address_space(1))) void*)g,
      (__attribute__((address_space(3))) void*)l, 16, 0, 0);
}

// ===========================================================================
// Diffusion: out[(b*512+node)*ldz + (1+tc)*C + coff0 + ch] =
//            sum_k Tpow[tc][node][k] * zT[ch][b*512+k]
// zT layout: [ch][16384]. grid.z = b*6 + tc. Dual-write ch<Fdual into zdual.
// BK=64, swizzled staging (source-XOR kc^(row&7), linear LDS dest, XOR read).
// 2-phase prefetch: stage(t+1) issued before compute(t); 1 barrier/tile.
// NTH = block threads (256 = 4 waves, 512 = 8 waves).
// ===========================================================================
template<int BM, int BN, int WR, int WC, int NTH>
__global__ __launch_bounds__(NTH) void gemm_diff(
    const u16* __restrict__ Tpow, const u16* __restrict__ zT,
    u16* __restrict__ zout, int ldz, int C, int coff0,
    u16* __restrict__ zdual, int Fdual)
{
  constexpr int BK = 64;
  constexpr int FM = BM / (WR * 16), FN = BN / (WC * 16);
  constexpr int SLOTS = (BM + BN) * 8;       // 16B slots per K-tile
  constexpr int NS = (SLOTS + NTH - 1) / NTH;
  constexpr int HALF = (BM + BN) * BK;       // u16 per LDS buffer
  __shared__ u16 sm[2 * HALF];
  const int tid = threadIdx.x, lane = tid & 63, wid = tid >> 6;
  const int wr = wid / WC, wc = wid % WC;
  const int l15 = lane & 15, l4 = lane >> 4;
  const int m0 = blockIdx.x * BM;
  const int y0 = blockIdx.y * BN;
  const int b = blockIdx.z / 6, tc = blockIdx.z % 6;
  const u16* A = Tpow + (long)tc * 262144;
  const u16* Bz = zT + (long)y0 * 16384 + b * 512;
  const int lb = (tid - lane) * 8;           // wave-uniform LDS dest (u16 units)

  const u16* gp[NS];
  #pragma unroll
  for (int i = 0; i < NS; i++) {
    int s = tid + i * NTH;
    int row = s >> 3, kc = s & 7;
    int kcg = kc ^ (row & 7);
    gp[i] = (row < BM) ? A + (long)(m0 + row) * 512 + kcg * 8
                       : Bz + (long)(row - BM) * 16384 + kcg * 8;
  }

  auto stage = [&](int buf) {
    u16* base = sm + buf * HALF + lb;
    #pragma unroll
    for (int i = 0; i < NS; i++) {
      if (i * NTH + NTH <= SLOTS || tid < SLOTS - i * NTH)
        glds16(gp[i], base + i * (NTH * 8));
    }
    #pragma unroll
    for (int i = 0; i < NS; i++) gp[i] += BK;
  };

  f32x4 acc[FM][FN] = {};
  auto compute = [&](int buf) {
    const u16* smc = sm + buf * HALF;
    #pragma unroll
    for (int kk = 0; kk < 2; kk++) {
      short8 af[FM], bf[FN];
      #pragma unroll
      for (int i = 0; i < FM; i++) {
        int ar = wr * FM * 16 + i * 16 + l15;
        af[i] = *(const short8*)&smc[ar * BK + (((kk * 4 + l4) ^ (ar & 7)) << 3)];
      }
      #pragma unroll
      for (int j = 0; j < FN; j++) {
        int br = wc * FN * 16 + j * 16 + l15;
        bf[j] = *(const short8*)&smc[BM * BK + br * BK + (((kk * 4 + l4) ^ (br & 7)) << 3)];
      }
      #pragma unroll
      for (int i = 0; i < FM; i++)
        #pragma unroll
        for (int j = 0; j < FN; j++)
          acc[i][j] = __builtin_amdgcn_mfma_f32_16x16x32_bf16(af[i], bf[j], acc[i][j], 0, 0, 0);
    }
  };

  stage(0);
  __syncthreads();
  int cur = 0;
  for (int t = 0; t < 7; t++) {              // NT = 512/64 = 8
    stage(cur ^ 1);
    compute(cur);
    __syncthreads();
    cur ^= 1;
  }
  compute(cur);

  const int tC = (1 + tc) * C;
  #pragma unroll
  for (int i = 0; i < FM; i++) {
    #pragma unroll
    for (int j = 0; j < FN; j++) {
      int node = m0 + wr * FM * 16 + i * 16 + l4 * 4;
      int ch = y0 + wc * FN * 16 + j * 16 + l15;
      #pragma unroll
      for (int rr = 0; rr < 4; rr++) {
        u16 v = f2bf(acc[i][j][rr]);
        long r = (long)b * 512 + node + rr;
        zout[r * ldz + tC + coff0 + ch] = v;
        if (Fdual && ch < Fdual) zdual[r * ldz + tC + ch] = v;
      }
    }
  }
}

// ===========================================================================
// Projection (giant-M): out(16384, Nout) = act(z(16384, K) @ W(Nout, K)^T + b)
// A rows read from Ag/Ac selected per K-chunk by ((k0>>7)&1) — lets L1 cand
// reuse z1g's h0-diffused halves (pass Ag==Ac when no split).
// MODE 1 (gates): n<128 -> rh=sig*hst -> zc[r*ldzc+Foff+n] + zTc[n*16384+r];
//                 n>=128 -> ubuf fp32.  MODE 2 (cand): tanh -> outbuf fp32.
// 4 waves; wave grid 2x2; FM=BM/32, FN=BN/32.
// ===========================================================================
template<int BM, int BN, int MODE>
__global__ __launch_bounds__(256) void gemm_proj(
    const u16* __restrict__ Ag, const u16* __restrict__ Ac, int ldA,
    const u16* __restrict__ W, int K,
    const float* __restrict__ bias,
    const float* __restrict__ hst,
    u16* __restrict__ zc, int ldzc, int Foff,
    u16* __restrict__ zTc,
    float* __restrict__ outbuf)
{
  constexpr int BK = 64;
  constexpr int FM = BM / 32, FN = BN / 32;   // 2x2 waves
  constexpr int NSA = BM / 32, NSB = BN / 32; // 32 rows per slot-group
  constexpr int HALF = (BM + BN) * BK;
  __shared__ u16 sm[2 * HALF];
  const int tid = threadIdx.x, lane = tid & 63, wid = tid >> 6;
  const int wr = wid >> 1, wc = wid & 1;
  const int l15 = lane & 15, l4 = lane >> 4;
  const int m0 = blockIdx.x * BM;
  const int n0 = blockIdx.y * BN;
  const int lb = (tid - lane) * 8;

  unsigned aoff[NSA];
  const u16* wp[NSB];
  #pragma unroll
  for (int i = 0; i < NSA; i++) {
    int s = tid + i * 256;
    int row = s >> 3, kc = s & 7;
    int kcg = kc ^ (row & 7);
    aoff[i] = (unsigned)((m0 + row) * ldA + kcg * 8);
  }
  #pragma unroll
  for (int i = 0; i < NSB; i++) {
    int s = tid + (NSA + i) * 256;
    int row = s >> 3, kc = s & 7;
    int kcg = kc ^ (row & 7);
    wp[i] = W + (long)(n0 + row - BM) * K + kcg * 8;
  }

  auto stage = [&](int buf, int koff) {
    u16* base = sm + buf * HALF + lb;
    const u16* ab = ((koff >> 7) & 1) ? Ac : Ag;
    #pragma unroll
    for (int i = 0; i < NSA; i++) glds16(ab + aoff[i] + koff, base + i * 2048);
    #pragma unroll
    for (int i = 0; i < NSB; i++) glds16(wp[i], base + (NSA + i) * 2048);
    #pragma unroll
    for (int i = 0; i < NSB; i++) wp[i] += BK;
  };

  f32x4 acc[FM][FN] = {};
  auto compute = [&](int buf) {
    const u16* smc = sm + buf * HALF;
    #pragma unroll
    for (int kk = 0; kk < 2; kk++) {
      short8 af[FM], bf[FN];
      #pragma unroll
      for (int i = 0; i < FM; i++) {
        int ar = wr * FM * 16 + i * 16 + l15;
        af[i] = *(const short8*)&smc[ar * BK + (((kk * 4 + l4) ^ (ar & 7)) << 3)];
      }
      #pragma unroll
      for (int j = 0; j < FN; j++) {
        int br = wc * FN * 16 + j * 16 + l15;
        bf[j] = *(const short8*)&smc[BM * BK + br * BK + (((kk * 4 + l4) ^ (br & 7)) << 3)];
      }
      #pragma unroll
      for (int i = 0; i < FM; i++)
        #pragma unroll
        for (int j = 0; j < FN; j++)
          acc[i][j] = __builtin_amdgcn_mfma_f32_16x16x32_bf16(af[i], bf[j], acc[i][j], 0, 0, 0);
    }
  };

  stage(0, 0);
  __syncthreads();
  int cur = 0;
  const int NT = K >> 6;
  for (int t = 1; t < NT; t++) {
    stage(cur ^ 1, t * 64);
    compute(cur);
    __syncthreads();
    cur ^= 1;
  }
  compute(cur);

  #pragma unroll
  for (int i = 0; i < FM; i++) {
    #pragma unroll
    for (int j = 0; j < FN; j++) {
      int mb = m0 + wr * FM * 16 + i * 16 + l4 * 4;
      int n = n0 + wc * FN * 16 + j * 16 + l15;
      #pragma unroll
      for (int rr = 0; rr < 4; rr++) {
        float v = acc[i][j][rr] + bias[n];
        long r = mb + rr;
        if constexpr (MODE == 1) {
          float g = 1.f / (1.f + expf(-v));
          if (n < 128) {
            float rh = g * hst[r * 128 + n];
            u16 hv = f2bf(rh);
            zc[r * ldzc + Foff + n] = hv;
            zTc[(long)n * 16384 + r] = hv;
          } else {
            outbuf[r * 128 + (n - 128)] = g;
          }
        } else {
          outbuf[r * 128 + n] = tanhf(v);
        }
      }
    }
  }
}

// ===========================================================================
// Fused GRU update + LayerNorm (H=128) + fan-out writes.
// Block: 64 nodes x 128 ch; grid (8, B).
// ===========================================================================
__global__ __launch_bounds__(256) void gru_ln(
    const float* __restrict__ ub, const float* __restrict__ cd,
    float* __restrict__ h, const float* __restrict__ gamma, const float* __restrict__ beta,
    u16* __restrict__ rm0, int ld0, int co0,
    u16* __restrict__ rm1, int ld1, int co1,
    u16* __restrict__ cm0, int ro0,
    u16* __restrict__ cm1, int ro1)
{
  __shared__ float hs[64][132];
  const int tid = threadIdx.x;
  const long b = blockIdx.y;
  const int n0 = blockIdx.x * 64;
  const long rbase = (b * 512 + n0) * 128;

  #pragma unroll
  for (int i = 0; i < 32; i++) {
    int idx = tid + i * 256;
    float u = ub[rbase + idx];
    float cc = cd[rbase + idx];
    float hv = h[rbase + idx];
    hs[idx >> 7][idx & 127] = (1.f - u) * hv + u * cc;
  }
  __syncthreads();

  const int rw = tid >> 2, sub = tid & 3;
  float s = 0.f, s2v = 0.f;
  #pragma unroll
  for (int i = 0; i < 32; i++) {
    float v = hs[rw][sub + 4 * i];
    s += v; s2v += v * v;
  }
  s += __shfl_xor(s, 1); s2v += __shfl_xor(s2v, 1);
  s += __shfl_xor(s, 2); s2v += __shfl_xor(s2v, 2);
  float mu = s * (1.f / 128.f);
  float var = s2v * (1.f / 128.f) - mu * mu;
  float rs = rsqrtf(var + 1e-5f);
  #pragma unroll
  for (int i = 0; i < 32; i++) {
    int c = sub + 4 * i;
    float v = (hs[rw][c] - mu) * rs * gamma[c] + beta[c];
    h[rbase + rw * 128 + c] = v;
    hs[rw][c] = v;
  }
  __syncthreads();

  #pragma unroll
  for (int i = 0; i < 32; i++) {
    int idx = tid + i * 256;
    int node = idx >> 7, c = idx & 127;
    u16 v = f2bf(hs[node][c]);
    long r = b * 512 + n0 + node;
    rm0[r * ld0 + co0 + c] = v;
    if (rm1) rm1[r * ld1 + co1 + c] = v;
  }
  const int c2 = tid >> 1, half = tid & 1;
  u16 tmp[32];
  #pragma unroll
  for (int i = 0; i < 32; i++) tmp[i] = f2bf(hs[half * 32 + i][c2]);
  const short8* tv = (const short8*)tmp;
  {
    long off = (long)(ro0 + c2) * 16384 + b * 512 + n0 + half * 32;
    #pragma unroll
    for (int q = 0; q < 4; q++) *(short8*)&cm0[off + q * 8] = tv[q];
  }
  if (cm1) {
    long off = (long)(ro1 + c2) * 16384 + b * 512 + n0 + half * 32;
    #pragma unroll
    for (int q = 0; q < 4; q++) *(short8*)&cm1[off + q * 8] = tv[q];
  }
}

// ===========================================================================
// small helpers
// ===========================================================================
__global__ __launch_bounds__(256) void xk(
    const float* __restrict__ xs, int t,
    u16* __restrict__ z0g, u16* __restrict__ z0c, u16* __restrict__ z0Tg)
{
  int r = blockIdx.x * 256 + threadIdx.x;       // 0..16383 = b*512+n
  int b = r >> 9, n = r & 511;
  const float* src = xs + (((long)b * 8 + t) * 512 + n) * 16;
  u16 tmp[16];
  #pragma unroll
  for (int f = 0; f < 16; f++) tmp[f] = f2bf(src[f]);
  const short8* tv = (const short8*)tmp;
  *(short8*)&z0g[(long)r * 1024] = tv[0];
  *(short8*)&z0g[(long)r * 1024 + 8] = tv[1];
  *(short8*)&z0c[(long)r * 1024] = tv[0];
  *(short8*)&z0c[(long)r * 1024 + 8] = tv[1];
  #pragma unroll
  for (int f = 0; f < 16; f++) z0Tg[(long)f * 16384 + r] = tmp[f];
}

__global__ void zero_cols(u16* __restrict__ z, int ld, int c0) {  // zero 128 cols
  int idx = blockIdx.x * 256 + threadIdx.x;     // 16384*16
  int r = idx >> 4, s = idx & 15;
  short8 zz = {};
  *(short8*)&z[(long)r * ld + c0 + s * 8] = zz;
}

__global__ void cvtT(const float* __restrict__ Tf, const float* __restrict__ Tb,
                     u16* __restrict__ Tpow, u16* __restrict__ TfT, u16* __restrict__ TbT)
{
  int idx = blockIdx.x * 256 + threadIdx.x;     // 262144
  int i = idx >> 9, j = idx & 511;
  const float* s = blockIdx.y ? Tb : Tf;
  u16* d = Tpow + (blockIdx.y ? 3 : 0) * 262144;
  u16* dT = blockIdx.y ? TbT : TfT;
  u16 v = f2bf(s[idx]);
  d[idx] = v;
  dT[(long)j * 512 + i] = v;
}

__global__ __launch_bounds__(256) void gemm_pow(
    const u16* __restrict__ A0, const u16* __restrict__ B0, u16* __restrict__ C0,
    const u16* __restrict__ A1, const u16* __restrict__ B1, u16* __restrict__ C1)
{
  constexpr int BM = 64, BN = 64, BK = 32;
  __shared__ u16 sm[(BM + BN) * BK];
  const int tid = threadIdx.x, lane = tid & 63, wid = tid >> 6;
  const int wr = wid >> 1, wc = wid & 1;
  const int l15 = lane & 15, l4 = lane >> 4;
  const int m0 = blockIdx.x * BM, n0 = blockIdx.y * BN;
  const u16* A = blockIdx.z ? A1 : A0;
  const u16* Bt = blockIdx.z ? B1 : B0;
  u16* Cc = blockIdx.z ? C1 : C0;

  f32x4 acc[2][2] = {};
  for (int k0 = 0; k0 < 512; k0 += BK) {
    for (int s = tid; s < (BM + BN) * 4; s += 256) {
      const u16* gp;
      if (s < BM * 4) { int m = s >> 2, kc = s & 3; gp = A + (long)(m0 + m) * 512 + k0 + kc * 8; }
      else { int q = s - BM * 4; int n = q >> 2, kc = q & 3; gp = Bt + (long)(n0 + n) * 512 + k0 + kc * 8; }
      glds16(gp, sm + (s - lane) * 8);
    }
    __syncthreads();
    short8 af[2], bf[2];
    #pragma unroll
    for (int i = 0; i < 2; i++)
      af[i] = *(const short8*)&sm[(wr * 32 + i * 16 + l15) * BK + l4 * 8];
    #pragma unroll
    for (int j = 0; j < 2; j++)
      bf[j] = *(const short8*)&sm[BM * BK + (wc * 32 + j * 16 + l15) * BK + l4 * 8];
    #pragma unroll
    for (int i = 0; i < 2; i++)
      #pragma unroll
      for (int j = 0; j < 2; j++)
        acc[i][j] = __builtin_amdgcn_mfma_f32_16x16x32_bf16(af[i], bf[j], acc[i][j], 0, 0, 0);
    __syncthreads();
  }
  #pragma unroll
  for (int i = 0; i < 2; i++)
    #pragma unroll
    for (int j = 0; j < 2; j++) {
      int mb = m0 + wr * 32 + i * 16 + l4 * 4;
      int n = n0 + wc * 32 + j * 16 + l15;
      #pragma unroll
      for (int rr = 0; rr < 4; rr++)
        Cc[(long)(mb + rr) * 512 + n] = f2bf(acc[i][j][rr]);
    }
}

__global__ void wt_cvt(const float* __restrict__ W, u16* __restrict__ Wt,
                       int Ksrc, int Kpad, int Nout) {
  long idx = (long)blockIdx.x * 256 + threadIdx.x;
  if (idx >= (long)Nout * Kpad) return;
  int o = (int)(idx / Kpad), k = (int)(idx % Kpad);
  Wt[idx] = f2bf(k < Ksrc ? W[(long)k * Nout + o] : 0.f);
}

// ===========================================================================
extern "C" void kernel_launch(void* const* d_in, const int* in_sizes, int n_in,
                              void* d_out, int out_size, void* d_ws, size_t ws_size,
                              hipStream_t stream) {
  const float* x_seq = (const float*)d_in[0];
  const float* Tf  = (const float*)d_in[1];
  const float* Tb  = (const float*)d_in[2];
  const float* Wg0 = (const float*)d_in[3];
  const float* bg0 = (const float*)d_in[4];
  const float* Wc0 = (const float*)d_in[5];
  const float* bc0 = (const float*)d_in[6];
  const float* g0  = (const float*)d_in[7];
  const float* be0 = (const float*)d_in[8];
  const float* Wg1 = (const float*)d_in[9];
  const float* bg1 = (const float*)d_in[10];
  const float* Wc1 = (const float*)d_in[11];
  const float* bc1 = (const float*)d_in[12];
  const float* g1  = (const float*)d_in[13];
  const float* be1 = (const float*)d_in[14];

  constexpr int B = 32, T = 8;
  constexpr long M = 16384;

  char* p = (char*)d_ws;
  auto carve = [&](size_t bytes) { char* r = p; p += (bytes + 255) & ~(size_t)255; return r; };
  u16* z0g  = (u16*)carve(M * 1024 * 2);
  u16* z0c  = (u16*)carve(M * 1024 * 2);
  u16* z1g  = (u16*)carve(M * 1792 * 2);
  u16* z1c  = (u16*)carve(M * 1792 * 2);
  u16* z0Tg = (u16*)carve(144L * M * 2);
  u16* z0Tc = (u16*)carve(128L * M * 2);
  u16* z1Tg = (u16*)carve(256L * M * 2);
  u16* z1Tc = (u16*)carve(128L * M * 2);
  float* ubuf = (float*)carve(M * 128 * 4);
  float* cbuf = (float*)carve(M * 128 * 4);
  u16* Tpow = (u16*)carve(6L * 512 * 512 * 2);   // Tf,Tf2,Tf3,Tb,Tb2,Tb3
  u16* TfT  = (u16*)carve(512L * 512 * 2);
  u16* TbT  = (u16*)carve(512L * 512 * 2);
  u16* Wg0t = (u16*)carve(256L * 1024 * 2);
  u16* Wc0t = (u16*)carve(128L * 1024 * 2);
  u16* Wg1t = (u16*)carve(256L * 1792 * 2);
  u16* Wc1t = (u16*)carve(128L * 1792 * 2);

  float* h0 = (float*)d_out;
  float* h1 = h0 + M * 128;

  hipMemsetAsync(d_out, 0, (size_t)out_size * 4, stream);
  zero_cols<<<1024, 256, 0, stream>>>(z0g, 1024, 16);
  zero_cols<<<1024, 256, 0, stream>>>(z1g, 1792, 128);
  hipMemsetAsync(z0Tg + 16L * M, 0, 128L * M * 2, stream);
  hipMemsetAsync(z1Tg + 128L * M, 0, 128L * M * 2, stream);

  cvtT<<<dim3(1024, 2), 256, 0, stream>>>(Tf, Tb, Tpow, TfT, TbT);
  gemm_pow<<<dim3(8, 8, 2), 256, 0, stream>>>(
      Tpow, TfT, Tpow + 1L * 262144, Tpow + 3L * 262144, TbT, Tpow + 4L * 262144);
  gemm_pow<<<dim3(8, 8, 2), 256, 0, stream>>>(
      Tpow + 1L * 262144, TfT, Tpow + 2L * 262144, Tpow + 4L * 262144, TbT, Tpow + 5L * 262144);
  wt_cvt<<<(256 * 1024 + 255) / 256, 256, 0, stream>>>(Wg0, Wg0t, 1008, 1024, 256);
  wt_cvt<<<(128 * 1024 + 255) / 256, 256, 0, stream>>>(Wc0, Wc0t, 1008, 1024, 128);
  wt_cvt<<<(256 * 1792 + 255) / 256, 256, 0, stream>>>(Wg1, Wg1t, 1792, 1792, 256);
  wt_cvt<<<(128 * 1792 + 255) / 256, 256, 0, stream>>>(Wc1, Wc1t, 1792, 1792, 128);

  for (int t = 0; t < T; t++) {
    // ======== layer 0 (C=144, Kpad=1024) ========
    xk<<<64, 256, 0, stream>>>(x_seq, t, z0g, z0c, z0Tg);
    // gates diffusion, all 144 ch, dual-write x-part (ch<16) into z0c
    gemm_diff<128, 48, 4, 1, 256><<<dim3(4, 3, 6 * B), 256, 0, stream>>>(
        Tpow, z0Tg, z0g, 1024, 144, 0, z0c, 16);
    gemm_proj<128, 64, 1><<<dim3(128, 4), 256, 0, stream>>>(
        z0g, z0g, 1024, Wg0t, 1024, bg0, h0, z0c, 1024, 16, z0Tc, ubuf);
    // cand diffusion: r*h half only (x-half reused via dual-write)
    gemm_diff<128, 128, 2, 4, 512><<<dim3(4, 1, 6 * B), 512, 0, stream>>>(
        Tpow, z0Tc, z0c, 1024, 144, 16, nullptr, 0);
    gemm_proj<64, 64, 2><<<dim3(256, 2), 256, 0, stream>>>(
        z0c, z0c, 1024, Wc0t, 1024, bc0, nullptr, nullptr, 0, 0, nullptr, cbuf);
    gru_ln<<<dim3(8, B), 256, 0, stream>>>(ubuf, cbuf, h0, g0, be0,
        z0g, 1024, 16, z1g, 1792, 0, z0Tg, 16, z1Tg, 0);
    // ======== layer 1 (C=256, Kpad=1792) ========
    gemm_diff<128, 128, 2, 4, 512><<<dim3(4, 2, 6 * B), 512, 0, stream>>>(
        Tpow, z1Tg, z1g, 1792, 256, 0, nullptr, 0);
    gemm_proj<128, 64, 1><<<dim3(128, 4), 256, 0, stream>>>(
        z1g, z1g, 1792, Wg1t, 1792, bg1, h1, z1c, 1792, 128, z1Tc, ubuf);
    gemm_diff<128, 128, 2, 4, 512><<<dim3(4, 1, 6 * B), 512, 0, stream>>>(
        Tpow, z1Tc, z1c, 1792, 256, 128, nullptr, 0);
    // cand proj: h0-diffused halves read from z1g, r*h1 halves from z1c
    gemm_proj<64, 64, 2><<<dim3(256, 2), 256, 0, stream>>>(
        z1g, z1c, 1792, Wc1t, 1792, bc1, nullptr, nullptr, 0, 0, nullptr, cbuf);
    gru_ln<<<dim3(8, B), 256, 0, stream>>>(ubuf, cbuf, h1, g1, be1,
        z1g, 1792, 128, nullptr, 0, 0, z1Tg, 128, nullptr, 0);
  }
}

// Round 8
// 1603.941 us; speedup vs baseline: 1.0714x; 1.0714x over previous
//
#include <hip/hip_runtime.h>
#include <hip/hip_bf16.h>
#include <math.h>

typedef unsigned short u16;
typedef __attribute__((ext_vector_type(8))) short short8;
typedef __attribute__((ext_vector_type(4))) float f32x4;

__device__ __forceinline__ u16 f2bf(float f) {
  union { float f; unsigned u; } v; v.f = f;
  unsigned r = v.u + 0x7fffu + ((v.u >> 16) & 1u);
  return (u16)(r >> 16);
}

// async global->LDS, 16B/lane. LDS dest is wave-uniform base; HW adds lane*16.
__device__ __forceinline__ void glds16(const u16* g, u16* l) {
  __builtin_amdgcn_global_load_lds(
      (const __attribute__((address_space(1))) void*)g,
      (__attribute__((address_space(3))) void*)l, 16, 0, 0);
}

// ===========================================================================
// Diffusion: out[(b*512+node)*ldz + (1+tc)*C + coff0 + ch] =
//            sum_k Tpow[tc][node][k] * zT[ch][b*512+k]
// zT layout: [ch][16384]. grid.z = b*6 + tc. Dual-write ch<Fdual into zdual.
// BK=64, swizzled staging (source-XOR kc^(row&7), linear LDS dest, XOR read).
// 2-phase prefetch: stage(t+1) issued before compute(t); 1 barrier/tile.
// ===========================================================================
template<int BM, int BN, int WR, int WC>
__global__ __launch_bounds__(256) void gemm_diff(
    const u16* __restrict__ Tpow, const u16* __restrict__ zT,
    u16* __restrict__ zout, int ldz, int C, int coff0,
    u16* __restrict__ zdual, int Fdual)
{
  constexpr int BK = 64;
  constexpr int FM = BM / (WR * 16), FN = BN / (WC * 16);
  constexpr int SLOTS = (BM + BN) * 8;       // 16B slots per K-tile
  constexpr int NS = (SLOTS + 255) / 256;
  constexpr int HALF = (BM + BN) * BK;       // u16 per LDS buffer
  __shared__ u16 sm[2 * HALF];
  const int tid = threadIdx.x, lane = tid & 63, wid = tid >> 6;
  const int wr = wid / WC, wc = wid % WC;
  const int l15 = lane & 15, l4 = lane >> 4;
  const int m0 = blockIdx.x * BM;
  const int y0 = blockIdx.y * BN;
  const int b = blockIdx.z / 6, tc = blockIdx.z % 6;
  const u16* A = Tpow + (long)tc * 262144;
  const u16* Bz = zT + (long)y0 * 16384 + b * 512;
  const int lb = (tid - lane) * 8;           // wave-uniform LDS dest (u16 units)

  const u16* gp[NS];
  #pragma unroll
  for (int i = 0; i < NS; i++) {
    int s = tid + i * 256;
    int row = s >> 3, kc = s & 7;
    int kcg = kc ^ (row & 7);
    gp[i] = (row < BM) ? A + (long)(m0 + row) * 512 + kcg * 8
                       : Bz + (long)(row - BM) * 16384 + kcg * 8;
  }

  auto stage = [&](int buf) {
    u16* base = sm + buf * HALF + lb;
    #pragma unroll
    for (int i = 0; i < NS; i++) {
      if (i * 256 + 256 <= SLOTS || tid < SLOTS - i * 256)
        glds16(gp[i], base + i * 2048);
    }
    #pragma unroll
    for (int i = 0; i < NS; i++) gp[i] += BK;
  };

  f32x4 acc[FM][FN] = {};
  auto compute = [&](int buf) {
    const u16* smc = sm + buf * HALF;
    #pragma unroll
    for (int kk = 0; kk < 2; kk++) {
      short8 af[FM], bf[FN];
      #pragma unroll
      for (int i = 0; i < FM; i++) {
        int ar = wr * FM * 16 + i * 16 + l15;
        af[i] = *(const short8*)&smc[ar * BK + (((kk * 4 + l4) ^ (ar & 7)) << 3)];
      }
      #pragma unroll
      for (int j = 0; j < FN; j++) {
        int br = wc * FN * 16 + j * 16 + l15;
        bf[j] = *(const short8*)&smc[BM * BK + br * BK + (((kk * 4 + l4) ^ (br & 7)) << 3)];
      }
      #pragma unroll
      for (int i = 0; i < FM; i++)
        #pragma unroll
        for (int j = 0; j < FN; j++)
          acc[i][j] = __builtin_amdgcn_mfma_f32_16x16x32_bf16(af[i], bf[j], acc[i][j], 0, 0, 0);
    }
  };

  stage(0);
  __syncthreads();
  int cur = 0;
  for (int t = 0; t < 7; t++) {              // NT = 512/64 = 8
    stage(cur ^ 1);
    compute(cur);
    __syncthreads();
    cur ^= 1;
  }
  compute(cur);

  const int tC = (1 + tc) * C;
  #pragma unroll
  for (int i = 0; i < FM; i++) {
    #pragma unroll
    for (int j = 0; j < FN; j++) {
      int node = m0 + wr * FM * 16 + i * 16 + l4 * 4;
      int ch = y0 + wc * FN * 16 + j * 16 + l15;
      #pragma unroll
      for (int rr = 0; rr < 4; rr++) {
        u16 v = f2bf(acc[i][j][rr]);
        long r = (long)b * 512 + node + rr;
        zout[r * ldz + tC + coff0 + ch] = v;
        if (Fdual && ch < Fdual) zdual[r * ldz + tC + ch] = v;
      }
    }
  }
}

// ===========================================================================
// Gates projection (giant-M): out(16384,256) = sigmoid(z @ W^T + b)
// n<128 -> rh=sig*hst -> zc[r*ldzc+Foff+n] + zTc[n*16384+r]; n>=128 -> ubuf.
// ===========================================================================
template<int BM, int BN>
__global__ __launch_bounds__(256) void gemm_proj(
    const u16* __restrict__ Az, int ldA,
    const u16* __restrict__ W, int K,
    const float* __restrict__ bias,
    const float* __restrict__ hst,
    u16* __restrict__ zc, int ldzc, int Foff,
    u16* __restrict__ zTc,
    float* __restrict__ outbuf)
{
  constexpr int BK = 64;
  constexpr int FM = BM / 32, FN = BN / 32;   // 2x2 waves
  constexpr int NSA = BM / 32, NSB = BN / 32;
  constexpr int HALF = (BM + BN) * BK;
  __shared__ u16 sm[2 * HALF];
  const int tid = threadIdx.x, lane = tid & 63, wid = tid >> 6;
  const int wr = wid >> 1, wc = wid & 1;
  const int l15 = lane & 15, l4 = lane >> 4;
  const int m0 = blockIdx.x * BM;
  const int n0 = blockIdx.y * BN;
  const int lb = (tid - lane) * 8;

  const u16* ap[NSA];
  const u16* wp[NSB];
  #pragma unroll
  for (int i = 0; i < NSA; i++) {
    int s = tid + i * 256;
    int row = s >> 3, kc = s & 7;
    int kcg = kc ^ (row & 7);
    ap[i] = Az + (long)(m0 + row) * ldA + kcg * 8;
  }
  #pragma unroll
  for (int i = 0; i < NSB; i++) {
    int s = tid + (NSA + i) * 256;
    int row = s >> 3, kc = s & 7;
    int kcg = kc ^ (row & 7);
    wp[i] = W + (long)(n0 + row - BM) * K + kcg * 8;
  }

  auto stage = [&](int buf) {
    u16* base = sm + buf * HALF + lb;
    #pragma unroll
    for (int i = 0; i < NSA; i++) { glds16(ap[i], base + i * 2048); ap[i] += BK; }
    #pragma unroll
    for (int i = 0; i < NSB; i++) { glds16(wp[i], base + (NSA + i) * 2048); wp[i] += BK; }
  };

  f32x4 acc[FM][FN] = {};
  auto compute = [&](int buf) {
    const u16* smc = sm + buf * HALF;
    #pragma unroll
    for (int kk = 0; kk < 2; kk++) {
      short8 af[FM], bf[FN];
      #pragma unroll
      for (int i = 0; i < FM; i++) {
        int ar = wr * FM * 16 + i * 16 + l15;
        af[i] = *(const short8*)&smc[ar * BK + (((kk * 4 + l4) ^ (ar & 7)) << 3)];
      }
      #pragma unroll
      for (int j = 0; j < FN; j++) {
        int br = wc * FN * 16 + j * 16 + l15;
        bf[j] = *(const short8*)&smc[BM * BK + br * BK + (((kk * 4 + l4) ^ (br & 7)) << 3)];
      }
      #pragma unroll
      for (int i = 0; i < FM; i++)
        #pragma unroll
        for (int j = 0; j < FN; j++)
          acc[i][j] = __builtin_amdgcn_mfma_f32_16x16x32_bf16(af[i], bf[j], acc[i][j], 0, 0, 0);
    }
  };

  stage(0);
  __syncthreads();
  int cur = 0;
  const int NT = K >> 6;
  for (int t = 1; t < NT; t++) {
    stage(cur ^ 1);
    compute(cur);
    __syncthreads();
    cur ^= 1;
  }
  compute(cur);

  #pragma unroll
  for (int i = 0; i < FM; i++) {
    #pragma unroll
    for (int j = 0; j < FN; j++) {
      int mb = m0 + wr * FM * 16 + i * 16 + l4 * 4;
      int n = n0 + wc * FN * 16 + j * 16 + l15;
      #pragma unroll
      for (int rr = 0; rr < 4; rr++) {
        float v = acc[i][j][rr] + bias[n];
        long r = mb + rr;
        float g = 1.f / (1.f + expf(-v));
        if (n < 128) {
          float rh = g * hst[r * 128 + n];
          u16 hv = f2bf(rh);
          zc[r * ldzc + Foff + n] = hv;
          zTc[(long)n * 16384 + r] = hv;
        } else {
          outbuf[r * 128 + (n - 128)] = g;
        }
      }
    }
  }
}

// ===========================================================================
// Fused candidate projection + GRU update + LayerNorm + fan-out.
// c = tanh(z @ Wc^T + b); hn = (1-u)h + u*c; h = LN(hn)*gamma+beta.
// BM=32 rows/block (within one batch), BN=128 = all H cols. grid (512).
// A K-chunks selected by bit7 of koff: Ag (bit7=0) / Ac (bit7=1).
// Fan-out: rm0/rm1 row-major bf16, cm0/cm1 ch-major bf16; optional next-step
// x staging (xs, tnext -> xz0g/xz0c/xz0T).
// ===========================================================================
__global__ __launch_bounds__(256) void proj_cand_gru(
    const u16* __restrict__ Ag, const u16* __restrict__ Ac, int ldA,
    const u16* __restrict__ W, int K,
    const float* __restrict__ bias,
    const float* __restrict__ ub, float* __restrict__ h,
    const float* __restrict__ gamma, const float* __restrict__ beta,
    u16* __restrict__ rm0, int ld0, int co0,
    u16* __restrict__ rm1, int ld1, int co1,
    u16* __restrict__ cm0, int ro0,
    u16* __restrict__ cm1, int ro1,
    const float* __restrict__ xs, int tnext,
    u16* __restrict__ xz0g, u16* __restrict__ xz0c, u16* __restrict__ xz0T)
{
  constexpr int BM = 32, BN = 128, BK = 64;
  constexpr int FM = 2, FN = 2;              // 4 waves, wave grid 1x4
  constexpr int NSA = 1, NSB = 4;
  constexpr int HALF = (BM + BN) * BK;       // 10240 u16
  __shared__ u16 sm[2 * HALF];               // 40 KB (reused for LN)
  const int tid = threadIdx.x, lane = tid & 63, wid = tid >> 6;
  const int wc = wid;                         // 0..3
  const int l15 = lane & 15, l4 = lane >> 4;
  const int m0 = blockIdx.x * BM;
  const int lb = (tid - lane) * 8;

  unsigned aoff[NSA];
  const u16* wp[NSB];
  #pragma unroll
  for (int i = 0; i < NSA; i++) {
    int s = tid + i * 256;
    int row = s >> 3, kc = s & 7;
    int kcg = kc ^ (row & 7);
    aoff[i] = (unsigned)((m0 + row) * ldA + kcg * 8);
  }
  #pragma unroll
  for (int i = 0; i < NSB; i++) {
    int s = tid + (NSA + i) * 256;
    int row = (s >> 3) - BM, kc = s & 7;
    int kcg = kc ^ ((row + BM) & 7);
    wp[i] = W + (long)row * K + kcg * 8;
  }

  auto stage = [&](int buf, int koff) {
    u16* base = sm + buf * HALF + lb;
    const u16* ab = ((koff >> 7) & 1) ? Ac : Ag;
    #pragma unroll
    for (int i = 0; i < NSA; i++) glds16(ab + aoff[i] + koff, base + i * 2048);
    #pragma unroll
    for (int i = 0; i < NSB; i++) { glds16(wp[i], base + (NSA + i) * 2048); wp[i] += BK; }
  };

  f32x4 acc[FM][FN] = {};
  auto compute = [&](int buf) {
    const u16* smc = sm + buf * HALF;
    #pragma unroll
    for (int kk = 0; kk < 2; kk++) {
      short8 af[FM], bf[FN];
      #pragma unroll
      for (int i = 0; i < FM; i++) {
        int ar = i * 16 + l15;
        af[i] = *(const short8*)&smc[ar * BK + (((kk * 4 + l4) ^ (ar & 7)) << 3)];
      }
      #pragma unroll
      for (int j = 0; j < FN; j++) {
        int br = wc * 32 + j * 16 + l15;
        bf[j] = *(const short8*)&smc[BM * BK + br * BK + (((kk * 4 + l4) ^ (br & 7)) << 3)];
      }
      #pragma unroll
      for (int i = 0; i < FM; i++)
        #pragma unroll
        for (int j = 0; j < FN; j++)
          acc[i][j] = __builtin_amdgcn_mfma_f32_16x16x32_bf16(af[i], bf[j], acc[i][j], 0, 0, 0);
    }
  };

  stage(0, 0);
  __syncthreads();
  int cur = 0;
  const int NT = K >> 6;
  for (int t = 1; t < NT; t++) {
    stage(cur ^ 1, t * 64);
    compute(cur);
    __syncthreads();
    cur ^= 1;
  }
  compute(cur);
  __syncthreads();                            // all waves done reading sm

  // GRU update into LDS (reuse sm as float hs[32][132])
  float* hs = (float*)sm;
  #pragma unroll
  for (int i = 0; i < FM; i++) {
    #pragma unroll
    for (int j = 0; j < FN; j++) {
      #pragma unroll
      for (int rr = 0; rr < 4; rr++) {
        int lrow = i * 16 + l4 * 4 + rr;
        int n = wc * 32 + j * 16 + l15;
        long r = m0 + lrow;
        float c = tanhf(acc[i][j][rr] + bias[n]);
        float u = ub[r * 128 + n];
        float hold = h[r * 128 + n];
        hs[lrow * 132 + n] = (1.f - u) * hold + u * c;
      }
    }
  }
  __syncthreads();

  // LayerNorm: 8 threads/row, 16 cols each
  {
    int row = tid >> 3, g = tid & 7;
    float s = 0.f, s2 = 0.f;
    #pragma unroll
    for (int k = 0; k < 16; k++) {
      float v = hs[row * 132 + g + 8 * k];
      s += v; s2 += v * v;
    }
    s += __shfl_xor(s, 1); s2 += __shfl_xor(s2, 1);
    s += __shfl_xor(s, 2); s2 += __shfl_xor(s2, 2);
    s += __shfl_xor(s, 4); s2 += __shfl_xor(s2, 4);
    float mu = s * (1.f / 128.f);
    float var = s2 * (1.f / 128.f) - mu * mu;
    float rs = rsqrtf(var + 1e-5f);
    long rb = (long)(m0 + row) * 128;
    #pragma unroll
    for (int k = 0; k < 16; k++) {
      int c = g + 8 * k;
      float v = (hs[row * 132 + c] - mu) * rs * gamma[c] + beta[c];
      h[rb + c] = v;
      hs[row * 132 + c] = v;
    }
  }
  __syncthreads();

  // row-major fan-out
  #pragma unroll
  for (int i = 0; i < 16; i++) {
    int idx = tid + i * 256;
    int row = idx >> 7, c = idx & 127;
    u16 v = f2bf(hs[row * 132 + c]);
    long r = m0 + row;
    rm0[r * ld0 + co0 + c] = v;
    if (rm1) rm1[r * ld1 + co1 + c] = v;
  }
  // ch-major fan-out
  {
    const int c2 = tid >> 1, half = tid & 1;
    u16 tmp[16];
    #pragma unroll
    for (int i = 0; i < 16; i++) tmp[i] = f2bf(hs[(half * 16 + i) * 132 + c2]);
    const short8* tv = (const short8*)tmp;
    long off = (long)(ro0 + c2) * 16384 + m0 + half * 16;
    *(short8*)&cm0[off] = tv[0];
    *(short8*)&cm0[off + 8] = tv[1];
    if (cm1) {
      long o2 = (long)(ro1 + c2) * 16384 + m0 + half * 16;
      *(short8*)&cm1[o2] = tv[0];
      *(short8*)&cm1[o2 + 8] = tv[1];
    }
  }
  // next-step x staging
  if (xs) {
    for (int e = tid; e < 512; e += 256) {
      int lrow = e >> 4, f = e & 15;
      long r = m0 + lrow;
      int b = (int)(r >> 9), n = (int)(r & 511);
      u16 v = f2bf(xs[(((long)b * 8 + tnext) * 512 + n) * 16 + f]);
      xz0g[r * 1024 + f] = v;
      xz0c[r * 1024 + f] = v;
      xz0T[(long)f * 16384 + r] = v;
    }
  }
}

// ===========================================================================
// small helpers
// ===========================================================================
__global__ __launch_bounds__(256) void xk(
    const float* __restrict__ xs, int t,
    u16* __restrict__ z0g, u16* __restrict__ z0c, u16* __restrict__ z0Tg)
{
  int r = blockIdx.x * 256 + threadIdx.x;       // 0..16383 = b*512+n
  int b = r >> 9, n = r & 511;
  const float* src = xs + (((long)b * 8 + t) * 512 + n) * 16;
  u16 tmp[16];
  #pragma unroll
  for (int f = 0; f < 16; f++) tmp[f] = f2bf(src[f]);
  const short8* tv = (const short8*)tmp;
  *(short8*)&z0g[(long)r * 1024] = tv[0];
  *(short8*)&z0g[(long)r * 1024 + 8] = tv[1];
  *(short8*)&z0c[(long)r * 1024] = tv[0];
  *(short8*)&z0c[(long)r * 1024 + 8] = tv[1];
  #pragma unroll
  for (int f = 0; f < 16; f++) z0Tg[(long)f * 16384 + r] = tmp[f];
}

__global__ void zero_cols(u16* __restrict__ z, int ld, int c0) {  // zero 128 cols
  int idx = blockIdx.x * 256 + threadIdx.x;     // 16384*16
  int r = idx >> 4, s = idx & 15;
  short8 zz = {};
  *(short8*)&z[(long)r * ld + c0 + s * 8] = zz;
}

__global__ void cvtT(const float* __restrict__ Tf, const float* __restrict__ Tb,
                     u16* __restrict__ Tpow, u16* __restrict__ TfT, u16* __restrict__ TbT)
{
  int idx = blockIdx.x * 256 + threadIdx.x;     // 262144
  int i = idx >> 9, j = idx & 511;
  const float* s = blockIdx.y ? Tb : Tf;
  u16* d = Tpow + (blockIdx.y ? 3 : 0) * 262144;
  u16* dT = blockIdx.y ? TbT : TfT;
  u16 v = f2bf(s[idx]);
  d[idx] = v;
  dT[(long)j * 512 + i] = v;
}

__global__ __launch_bounds__(256) void gemm_pow(
    const u16* __restrict__ A0, const u16* __restrict__ B0, u16* __restrict__ C0,
    const u16* __restrict__ A1, const u16* __restrict__ B1, u16* __restrict__ C1)
{
  constexpr int BM = 64, BN = 64, BK = 32;
  __shared__ u16 sm[(BM + BN) * BK];
  const int tid = threadIdx.x, lane = tid & 63, wid = tid >> 6;
  const int wr = wid >> 1, wc = wid & 1;
  const int l15 = lane & 15, l4 = lane >> 4;
  const int m0 = blockIdx.x * BM, n0 = blockIdx.y * BN;
  const u16* A = blockIdx.z ? A1 : A0;
  const u16* Bt = blockIdx.z ? B1 : B0;
  u16* Cc = blockIdx.z ? C1 : C0;

  f32x4 acc[2][2] = {};
  for (int k0 = 0; k0 < 512; k0 += BK) {
    for (int s = tid; s < (BM + BN) * 4; s += 256) {
      const u16* gp;
      if (s < BM * 4) { int m = s >> 2, kc = s & 3; gp = A + (long)(m0 + m) * 512 + k0 + kc * 8; }
      else { int q = s - BM * 4; int n = q >> 2, kc = q & 3; gp = Bt + (long)(n0 + n) * 512 + k0 + kc * 8; }
      glds16(gp, sm + (s - lane) * 8);
    }
    __syncthreads();
    short8 af[2], bf[2];
    #pragma unroll
    for (int i = 0; i < 2; i++)
      af[i] = *(const short8*)&sm[(wr * 32 + i * 16 + l15) * BK + l4 * 8];
    #pragma unroll
    for (int j = 0; j < 2; j++)
      bf[j] = *(const short8*)&sm[BM * BK + (wc * 32 + j * 16 + l15) * BK + l4 * 8];
    #pragma unroll
    for (int i = 0; i < 2; i++)
      #pragma unroll
      for (int j = 0; j < 2; j++)
        acc[i][j] = __builtin_amdgcn_mfma_f32_16x16x32_bf16(af[i], bf[j], acc[i][j], 0, 0, 0);
    __syncthreads();
  }
  #pragma unroll
  for (int i = 0; i < 2; i++)
    #pragma unroll
    for (int j = 0; j < 2; j++) {
      int mb = m0 + wr * 32 + i * 16 + l4 * 4;
      int n = n0 + wc * 32 + j * 16 + l15;
      #pragma unroll
      for (int rr = 0; rr < 4; rr++)
        Cc[(long)(mb + rr) * 512 + n] = f2bf(acc[i][j][rr]);
    }
}

__global__ void wt_cvt(const float* __restrict__ W, u16* __restrict__ Wt,
                       int Ksrc, int Kpad, int Nout) {
  long idx = (long)blockIdx.x * 256 + threadIdx.x;
  if (idx >= (long)Nout * Kpad) return;
  int o = (int)(idx / Kpad), k = (int)(idx % Kpad);
  Wt[idx] = f2bf(k < Ksrc ? W[(long)k * Nout + o] : 0.f);
}

// ===========================================================================
extern "C" void kernel_launch(void* const* d_in, const int* in_sizes, int n_in,
                              void* d_out, int out_size, void* d_ws, size_t ws_size,
                              hipStream_t stream) {
  const float* x_seq = (const float*)d_in[0];
  const float* Tf  = (const float*)d_in[1];
  const float* Tb  = (const float*)d_in[2];
  const float* Wg0 = (const float*)d_in[3];
  const float* bg0 = (const float*)d_in[4];
  const float* Wc0 = (const float*)d_in[5];
  const float* bc0 = (const float*)d_in[6];
  const float* g0  = (const float*)d_in[7];
  const float* be0 = (const float*)d_in[8];
  const float* Wg1 = (const float*)d_in[9];
  const float* bg1 = (const float*)d_in[10];
  const float* Wc1 = (const float*)d_in[11];
  const float* bc1 = (const float*)d_in[12];
  const float* g1  = (const float*)d_in[13];
  const float* be1 = (const float*)d_in[14];

  constexpr int B = 32, T = 8;
  constexpr long M = 16384;

  char* p = (char*)d_ws;
  auto carve = [&](size_t bytes) { char* r = p; p += (bytes + 255) & ~(size_t)255; return r; };
  u16* z0g  = (u16*)carve(M * 1024 * 2);
  u16* z0c  = (u16*)carve(M * 1024 * 2);
  u16* z1g  = (u16*)carve(M * 1792 * 2);
  u16* z1c  = (u16*)carve(M * 1792 * 2);
  u16* z0Tg = (u16*)carve(144L * M * 2);
  u16* z0Tc = (u16*)carve(128L * M * 2);
  u16* z1Tg = (u16*)carve(256L * M * 2);
  u16* z1Tc = (u16*)carve(128L * M * 2);
  float* ubuf = (float*)carve(M * 128 * 4);
  u16* Tpow = (u16*)carve(6L * 512 * 512 * 2);   // Tf,Tf2,Tf3,Tb,Tb2,Tb3
  u16* TfT  = (u16*)carve(512L * 512 * 2);
  u16* TbT  = (u16*)carve(512L * 512 * 2);
  u16* Wg0t = (u16*)carve(256L * 1024 * 2);
  u16* Wc0t = (u16*)carve(128L * 1024 * 2);
  u16* Wg1t = (u16*)carve(256L * 1792 * 2);
  u16* Wc1t = (u16*)carve(128L * 1792 * 2);

  float* h0 = (float*)d_out;
  float* h1 = h0 + M * 128;

  hipMemsetAsync(d_out, 0, (size_t)out_size * 4, stream);
  zero_cols<<<1024, 256, 0, stream>>>(z0g, 1024, 16);
  zero_cols<<<1024, 256, 0, stream>>>(z1g, 1792, 128);
  hipMemsetAsync(z0Tg + 16L * M, 0, 128L * M * 2, stream);
  hipMemsetAsync(z1Tg + 128L * M, 0, 128L * M * 2, stream);

  cvtT<<<dim3(1024, 2), 256, 0, stream>>>(Tf, Tb, Tpow, TfT, TbT);
  gemm_pow<<<dim3(8, 8, 2), 256, 0, stream>>>(
      Tpow, TfT, Tpow + 1L * 262144, Tpow + 3L * 262144, TbT, Tpow + 4L * 262144);
  gemm_pow<<<dim3(8, 8, 2), 256, 0, stream>>>(
      Tpow + 1L * 262144, TfT, Tpow + 2L * 262144, Tpow + 4L * 262144, TbT, Tpow + 5L * 262144);
  wt_cvt<<<(256 * 1024 + 255) / 256, 256, 0, stream>>>(Wg0, Wg0t, 1008, 1024, 256);
  wt_cvt<<<(128 * 1024 + 255) / 256, 256, 0, stream>>>(Wc0, Wc0t, 1008, 1024, 128);
  wt_cvt<<<(256 * 1792 + 255) / 256, 256, 0, stream>>>(Wg1, Wg1t, 1792, 1792, 256);
  wt_cvt<<<(128 * 1792 + 255) / 256, 256, 0, stream>>>(Wc1, Wc1t, 1792, 1792, 128);

  xk<<<64, 256, 0, stream>>>(x_seq, 0, z0g, z0c, z0Tg);   // x(t=0)

  for (int t = 0; t < T; t++) {
    // ======== layer 0 (C=144, Kpad=1024) ========
    gemm_diff<128, 48, 4, 1><<<dim3(4, 3, 6 * B), 256, 0, stream>>>(
        Tpow, z0Tg, z0g, 1024, 144, 0, z0c, 16);
    gemm_proj<64, 64><<<dim3(256, 4), 256, 0, stream>>>(
        z0g, 1024, Wg0t, 1024, bg0, h0, z0c, 1024, 16, z0Tc, ubuf);
    gemm_diff<128, 64, 2, 2><<<dim3(4, 2, 6 * B), 256, 0, stream>>>(
        Tpow, z0Tc, z0c, 1024, 144, 16, nullptr, 0);
    proj_cand_gru<<<512, 256, 0, stream>>>(
        z0c, z0c, 1024, Wc0t, 1024, bc0, ubuf, h0, g0, be0,
        z0g, 1024, 16, z1g, 1792, 0, z0Tg, 16, z1Tg, 0,
        nullptr, 0, nullptr, nullptr, nullptr);
    // ======== layer 1 (C=256, Kpad=1792) ========
    gemm_diff<128, 64, 2, 2><<<dim3(4, 4, 6 * B), 256, 0, stream>>>(
        Tpow, z1Tg, z1g, 1792, 256, 0, nullptr, 0);
    gemm_proj<64, 64><<<dim3(256, 4), 256, 0, stream>>>(
        z1g, 1792, Wg1t, 1792, bg1, h1, z1c, 1792, 128, z1Tc, ubuf);
    gemm_diff<128, 64, 2, 2><<<dim3(4, 2, 6 * B), 256, 0, stream>>>(
        Tpow, z1Tc, z1c, 1792, 256, 128, nullptr, 0);
    // cand proj: h0-diffused halves from z1g, r*h1 halves from z1c;
    // also stages x(t+1) for the next step.
    proj_cand_gru<<<512, 256, 0, stream>>>(
        z1g, z1c, 1792, Wc1t, 1792, bc1, ubuf, h1, g1, be1,
        z1g, 1792, 128, nullptr, 0, 0, z1Tg, 128, nullptr, 0,
        (t < T - 1) ? x_seq : nullptr, t + 1, z0g, z0c, z0Tg);
  }
}

// Round 9
// 1582.856 us; speedup vs baseline: 1.0857x; 1.0133x over previous
//
#include <hip/hip_runtime.h>
#include <hip/hip_bf16.h>
#include <math.h>

typedef unsigned short u16;
typedef __attribute__((ext_vector_type(8))) short short8;
typedef __attribute__((ext_vector_type(4))) float f32x4;

__device__ __forceinline__ u16 f2bf(float f) {
  union { float f; unsigned u; } v; v.f = f;
  unsigned r = v.u + 0x7fffu + ((v.u >> 16) & 1u);
  return (u16)(r >> 16);
}

// async global->LDS, 16B/lane. LDS dest is wave-uniform base; HW adds lane*16.
__device__ __forceinline__ void glds16(const u16* g, u16* l) {
  __builtin_amdgcn_global_load_lds(
      (const __attribute__((address_space(1))) void*)g,
      (__attribute__((address_space(3))) void*)l, 16, 0, 0);
}

// Counted-vmcnt barrier (T4): wait until only N VMEM ops remain in flight
// (the prefetch), then block-barrier. Compiler fences pin LDS reads below.
template<int N> __device__ __forceinline__ void kbar() {
  asm volatile("s_waitcnt vmcnt(%0)" :: "n"(N) : "memory");
  __builtin_amdgcn_s_barrier();
  asm volatile("" ::: "memory");
}
// Plain barrier (no drain): protects buffer reuse.
__device__ __forceinline__ void bar2() {
  asm volatile("" ::: "memory");
  __builtin_amdgcn_s_barrier();
  asm volatile("" ::: "memory");
}

// ===========================================================================
// Diffusion: out[(b*512+node)*ldz + (1+tc)*C + coff0 + ch] =
//            sum_k Tpow[tc][node][k] * zT[ch][b*512+k]
// zT layout: [ch][16384]. grid.z = b*6 + tc. Dual-write ch<Fdual into zdual.
// BK=64, swizzled staging (source-XOR kc^(row&7), linear LDS dest, XOR read).
// 2-phase prefetch with counted vmcnt: prefetch stays in flight across the
// barrier; vmcnt(0) only in the epilogue.
// ===========================================================================
template<int BM, int BN, int WR, int WC>
__global__ __launch_bounds__(256) void gemm_diff(
    const u16* __restrict__ Tpow, const u16* __restrict__ zT,
    u16* __restrict__ zout, int ldz, int C, int coff0,
    u16* __restrict__ zdual, int Fdual)
{
  constexpr int BK = 64;
  constexpr int FM = BM / (WR * 16), FN = BN / (WC * 16);
  constexpr int SLOTS = (BM + BN) * 8;       // 16B slots per K-tile
  constexpr int NS = (SLOTS + 255) / 256;
  constexpr int VMIN = SLOTS / 256;          // conservative per-wave count
  constexpr int HALF = (BM + BN) * BK;       // u16 per LDS buffer
  __shared__ u16 sm[2 * HALF];
  const int tid = threadIdx.x, lane = tid & 63, wid = tid >> 6;
  const int wr = wid / WC, wc = wid % WC;
  const int l15 = lane & 15, l4 = lane >> 4;
  const int m0 = blockIdx.x * BM;
  const int y0 = blockIdx.y * BN;
  const int b = blockIdx.z / 6, tc = blockIdx.z % 6;
  const u16* A = Tpow + (long)tc * 262144;
  const u16* Bz = zT + (long)y0 * 16384 + b * 512;
  const int lb = (tid - lane) * 8;           // wave-uniform LDS dest (u16 units)

  const u16* gp[NS];
  #pragma unroll
  for (int i = 0; i < NS; i++) {
    int s = tid + i * 256;
    int row = s >> 3, kc = s & 7;
    int kcg = kc ^ (row & 7);
    gp[i] = (row < BM) ? A + (long)(m0 + row) * 512 + kcg * 8
                       : Bz + (long)(row - BM) * 16384 + kcg * 8;
  }

  auto stage = [&](int buf) {
    u16* base = sm + buf * HALF + lb;
    #pragma unroll
    for (int i = 0; i < NS; i++) {
      if (i * 256 + 256 <= SLOTS || tid < SLOTS - i * 256)
        glds16(gp[i], base + i * 2048);
    }
    #pragma unroll
    for (int i = 0; i < NS; i++) gp[i] += BK;
  };

  f32x4 acc[FM][FN] = {};
  auto compute = [&](int buf) {
    const u16* smc = sm + buf * HALF;
    #pragma unroll
    for (int kk = 0; kk < 2; kk++) {
      short8 af[FM], bf[FN];
      #pragma unroll
      for (int i = 0; i < FM; i++) {
        int ar = wr * FM * 16 + i * 16 + l15;
        af[i] = *(const short8*)&smc[ar * BK + (((kk * 4 + l4) ^ (ar & 7)) << 3)];
      }
      #pragma unroll
      for (int j = 0; j < FN; j++) {
        int br = wc * FN * 16 + j * 16 + l15;
        bf[j] = *(const short8*)&smc[BM * BK + br * BK + (((kk * 4 + l4) ^ (br & 7)) << 3)];
      }
      #pragma unroll
      for (int i = 0; i < FM; i++)
        #pragma unroll
        for (int j = 0; j < FN; j++)
          acc[i][j] = __builtin_amdgcn_mfma_f32_16x16x32_bf16(af[i], bf[j], acc[i][j], 0, 0, 0);
    }
  };

  stage(0);
  int cur = 0;
  for (int t = 0; t < 7; t++) {              // NT = 512/64 = 8
    stage(cur ^ 1);
    kbar<VMIN>();                            // cur's loads done; prefetch in flight
    compute(cur);
    bar2();                                  // all waves done reading cur
    cur ^= 1;
  }
  kbar<0>();                                 // drain last tile
  compute(cur);

  const int tC = (1 + tc) * C;
  #pragma unroll
  for (int i = 0; i < FM; i++) {
    #pragma unroll
    for (int j = 0; j < FN; j++) {
      int node = m0 + wr * FM * 16 + i * 16 + l4 * 4;
      int ch = y0 + wc * FN * 16 + j * 16 + l15;
      #pragma unroll
      for (int rr = 0; rr < 4; rr++) {
        u16 v = f2bf(acc[i][j][rr]);
        long r = (long)b * 512 + node + rr;
        zout[r * ldz + tC + coff0 + ch] = v;
        if (Fdual && ch < Fdual) zdual[r * ldz + tC + ch] = v;
      }
    }
  }
}

// ===========================================================================
// Gates projection (giant-M): out(16384,256) = sigmoid(z @ W^T + b)
// n<128 -> rh=sig*hst -> zc[r*ldzc+Foff+n] + zTc[n*16384+r]; n>=128 -> ubuf.
// ===========================================================================
template<int BM, int BN>
__global__ __launch_bounds__(256) void gemm_proj(
    const u16* __restrict__ Az, int ldA,
    const u16* __restrict__ W, int K,
    const float* __restrict__ bias,
    const float* __restrict__ hst,
    u16* __restrict__ zc, int ldzc, int Foff,
    u16* __restrict__ zTc,
    float* __restrict__ outbuf)
{
  constexpr int BK = 64;
  constexpr int FM = BM / 32, FN = BN / 32;   // 2x2 waves
  constexpr int NSA = BM / 32, NSB = BN / 32;
  constexpr int VMIN = NSA + NSB;
  constexpr int HALF = (BM + BN) * BK;
  __shared__ u16 sm[2 * HALF];
  const int tid = threadIdx.x, lane = tid & 63, wid = tid >> 6;
  const int wr = wid >> 1, wc = wid & 1;
  const int l15 = lane & 15, l4 = lane >> 4;
  const int m0 = blockIdx.x * BM;
  const int n0 = blockIdx.y * BN;
  const int lb = (tid - lane) * 8;

  const u16* ap[NSA];
  const u16* wp[NSB];
  #pragma unroll
  for (int i = 0; i < NSA; i++) {
    int s = tid + i * 256;
    int row = s >> 3, kc = s & 7;
    int kcg = kc ^ (row & 7);
    ap[i] = Az + (long)(m0 + row) * ldA + kcg * 8;
  }
  #pragma unroll
  for (int i = 0; i < NSB; i++) {
    int s = tid + (NSA + i) * 256;
    int row = s >> 3, kc = s & 7;
    int kcg = kc ^ (row & 7);
    wp[i] = W + (long)(n0 + row - BM) * K + kcg * 8;
  }

  auto stage = [&](int buf) {
    u16* base = sm + buf * HALF + lb;
    #pragma unroll
    for (int i = 0; i < NSA; i++) { glds16(ap[i], base + i * 2048); ap[i] += BK; }
    #pragma unroll
    for (int i = 0; i < NSB; i++) { glds16(wp[i], base + (NSA + i) * 2048); wp[i] += BK; }
  };

  f32x4 acc[FM][FN] = {};
  auto compute = [&](int buf) {
    const u16* smc = sm + buf * HALF;
    #pragma unroll
    for (int kk = 0; kk < 2; kk++) {
      short8 af[FM], bf[FN];
      #pragma unroll
      for (int i = 0; i < FM; i++) {
        int ar = wr * FM * 16 + i * 16 + l15;
        af[i] = *(const short8*)&smc[ar * BK + (((kk * 4 + l4) ^ (ar & 7)) << 3)];
      }
      #pragma unroll
      for (int j = 0; j < FN; j++) {
        int br = wc * FN * 16 + j * 16 + l15;
        bf[j] = *(const short8*)&smc[BM * BK + br * BK + (((kk * 4 + l4) ^ (br & 7)) << 3)];
      }
      #pragma unroll
      for (int i = 0; i < FM; i++)
        #pragma unroll
        for (int j = 0; j < FN; j++)
          acc[i][j] = __builtin_amdgcn_mfma_f32_16x16x32_bf16(af[i], bf[j], acc[i][j], 0, 0, 0);
    }
  };

  stage(0);
  int cur = 0;
  const int NT = K >> 6;
  for (int t = 1; t < NT; t++) {
    stage(cur ^ 1);
    kbar<VMIN>();
    compute(cur);
    bar2();
    cur ^= 1;
  }
  kbar<0>();
  compute(cur);

  #pragma unroll
  for (int i = 0; i < FM; i++) {
    #pragma unroll
    for (int j = 0; j < FN; j++) {
      int mb = m0 + wr * FM * 16 + i * 16 + l4 * 4;
      int n = n0 + wc * FN * 16 + j * 16 + l15;
      #pragma unroll
      for (int rr = 0; rr < 4; rr++) {
        float v = acc[i][j][rr] + bias[n];
        long r = mb + rr;
        float g = 1.f / (1.f + expf(-v));
        if (n < 128) {
          float rh = g * hst[r * 128 + n];
          u16 hv = f2bf(rh);
          zc[r * ldzc + Foff + n] = hv;
          zTc[(long)n * 16384 + r] = hv;
        } else {
          outbuf[r * 128 + (n - 128)] = g;
        }
      }
    }
  }
}

// ===========================================================================
// Fused candidate projection + GRU update + LayerNorm + fan-out.
// c = tanh(z @ Wc^T + b); hn = (1-u)h + u*c; h = LN(hn)*gamma+beta.
// BM=32 rows/block (within one batch), BN=128 = all H cols. grid (512).
// A K-chunks selected by bit7 of koff: Ag (bit7=0) / Ac (bit7=1).
// ===========================================================================
__global__ __launch_bounds__(256) void proj_cand_gru(
    const u16* __restrict__ Ag, const u16* __restrict__ Ac, int ldA,
    const u16* __restrict__ W, int K,
    const float* __restrict__ bias,
    const float* __restrict__ ub, float* __restrict__ h,
    const float* __restrict__ gamma, const float* __restrict__ beta,
    u16* __restrict__ rm0, int ld0, int co0,
    u16* __restrict__ rm1, int ld1, int co1,
    u16* __restrict__ cm0, int ro0,
    u16* __restrict__ cm1, int ro1,
    const float* __restrict__ xs, int tnext,
    u16* __restrict__ xz0g, u16* __restrict__ xz0c, u16* __restrict__ xz0T)
{
  constexpr int BM = 32, BN = 128, BK = 64;
  constexpr int FM = 2, FN = 2;              // 4 waves, wave grid 1x4
  constexpr int NSA = 1, NSB = 4;
  constexpr int HALF = (BM + BN) * BK;       // 10240 u16
  __shared__ u16 sm[2 * HALF];               // 40 KB (reused for LN)
  const int tid = threadIdx.x, lane = tid & 63, wid = tid >> 6;
  const int wc = wid;                         // 0..3
  const int l15 = lane & 15, l4 = lane >> 4;
  const int m0 = blockIdx.x * BM;
  const int lb = (tid - lane) * 8;

  unsigned aoff[NSA];
  const u16* wp[NSB];
  #pragma unroll
  for (int i = 0; i < NSA; i++) {
    int s = tid + i * 256;
    int row = s >> 3, kc = s & 7;
    int kcg = kc ^ (row & 7);
    aoff[i] = (unsigned)((m0 + row) * ldA + kcg * 8);
  }
  #pragma unroll
  for (int i = 0; i < NSB; i++) {
    int s = tid + (NSA + i) * 256;
    int row = (s >> 3) - BM, kc = s & 7;
    int kcg = kc ^ ((row + BM) & 7);
    wp[i] = W + (long)row * K + kcg * 8;
  }

  auto stage = [&](int buf, int koff) {
    u16* base = sm + buf * HALF + lb;
    const u16* ab = ((koff >> 7) & 1) ? Ac : Ag;
    #pragma unroll
    for (int i = 0; i < NSA; i++) glds16(ab + aoff[i] + koff, base + i * 2048);
    #pragma unroll
    for (int i = 0; i < NSB; i++) { glds16(wp[i], base + (NSA + i) * 2048); wp[i] += BK; }
  };

  f32x4 acc[FM][FN] = {};
  auto compute = [&](int buf) {
    const u16* smc = sm + buf * HALF;
    #pragma unroll
    for (int kk = 0; kk < 2; kk++) {
      short8 af[FM], bf[FN];
      #pragma unroll
      for (int i = 0; i < FM; i++) {
        int ar = i * 16 + l15;
        af[i] = *(const short8*)&smc[ar * BK + (((kk * 4 + l4) ^ (ar & 7)) << 3)];
      }
      #pragma unroll
      for (int j = 0; j < FN; j++) {
        int br = wc * 32 + j * 16 + l15;
        bf[j] = *(const short8*)&smc[BM * BK + br * BK + (((kk * 4 + l4) ^ (br & 7)) << 3)];
      }
      #pragma unroll
      for (int i = 0; i < FM; i++)
        #pragma unroll
        for (int j = 0; j < FN; j++)
          acc[i][j] = __builtin_amdgcn_mfma_f32_16x16x32_bf16(af[i], bf[j], acc[i][j], 0, 0, 0);
    }
  };

  stage(0, 0);
  int cur = 0;
  const int NT = K >> 6;
  for (int t = 1; t < NT; t++) {
    stage(cur ^ 1, t * 64);
    kbar<5>();                               // NSA+NSB = 5
    compute(cur);
    bar2();
    cur ^= 1;
  }
  kbar<0>();
  compute(cur);
  __syncthreads();                            // all waves done reading sm

  // GRU update into LDS (reuse sm as float hs[32][132])
  float* hs = (float*)sm;
  #pragma unroll
  for (int i = 0; i < FM; i++) {
    #pragma unroll
    for (int j = 0; j < FN; j++) {
      #pragma unroll
      for (int rr = 0; rr < 4; rr++) {
        int lrow = i * 16 + l4 * 4 + rr;
        int n = wc * 32 + j * 16 + l15;
        long r = m0 + lrow;
        float c = tanhf(acc[i][j][rr] + bias[n]);
        float u = ub[r * 128 + n];
        float hold = h[r * 128 + n];
        hs[lrow * 132 + n] = (1.f - u) * hold + u * c;
      }
    }
  }
  __syncthreads();

  // LayerNorm: 8 threads/row, 16 cols each
  {
    int row = tid >> 3, g = tid & 7;
    float s = 0.f, s2 = 0.f;
    #pragma unroll
    for (int k = 0; k < 16; k++) {
      float v = hs[row * 132 + g + 8 * k];
      s += v; s2 += v * v;
    }
    s += __shfl_xor(s, 1); s2 += __shfl_xor(s2, 1);
    s += __shfl_xor(s, 2); s2 += __shfl_xor(s2, 2);
    s += __shfl_xor(s, 4); s2 += __shfl_xor(s2, 4);
    float mu = s * (1.f / 128.f);
    float var = s2 * (1.f / 128.f) - mu * mu;
    float rs = rsqrtf(var + 1e-5f);
    long rb = (long)(m0 + row) * 128;
    #pragma unroll
    for (int k = 0; k < 16; k++) {
      int c = g + 8 * k;
      float v = (hs[row * 132 + c] - mu) * rs * gamma[c] + beta[c];
      h[rb + c] = v;
      hs[row * 132 + c] = v;
    }
  }
  __syncthreads();

  // row-major fan-out
  #pragma unroll
  for (int i = 0; i < 16; i++) {
    int idx = tid + i * 256;
    int row = idx >> 7, c = idx & 127;
    u16 v = f2bf(hs[row * 132 + c]);
    long r = m0 + row;
    rm0[r * ld0 + co0 + c] = v;
    if (rm1) rm1[r * ld1 + co1 + c] = v;
  }
  // ch-major fan-out
  {
    const int c2 = tid >> 1, half = tid & 1;
    u16 tmp[16];
    #pragma unroll
    for (int i = 0; i < 16; i++) tmp[i] = f2bf(hs[(half * 16 + i) * 132 + c2]);
    const short8* tv = (const short8*)tmp;
    long off = (long)(ro0 + c2) * 16384 + m0 + half * 16;
    *(short8*)&cm0[off] = tv[0];
    *(short8*)&cm0[off + 8] = tv[1];
    if (cm1) {
      long o2 = (long)(ro1 + c2) * 16384 + m0 + half * 16;
      *(short8*)&cm1[o2] = tv[0];
      *(short8*)&cm1[o2 + 8] = tv[1];
    }
  }
  // next-step x staging
  if (xs) {
    for (int e = tid; e < 512; e += 256) {
      int lrow = e >> 4, f = e & 15;
      long r = m0 + lrow;
      int b = (int)(r >> 9), n = (int)(r & 511);
      u16 v = f2bf(xs[(((long)b * 8 + tnext) * 512 + n) * 16 + f]);
      xz0g[r * 1024 + f] = v;
      xz0c[r * 1024 + f] = v;
      xz0T[(long)f * 16384 + r] = v;
    }
  }
}

// ===========================================================================
// small helpers
// ===========================================================================
__global__ __launch_bounds__(256) void xk(
    const float* __restrict__ xs, int t,
    u16* __restrict__ z0g, u16* __restrict__ z0c, u16* __restrict__ z0Tg)
{
  int r = blockIdx.x * 256 + threadIdx.x;       // 0..16383 = b*512+n
  int b = r >> 9, n = r & 511;
  const float* src = xs + (((long)b * 8 + t) * 512 + n) * 16;
  u16 tmp[16];
  #pragma unroll
  for (int f = 0; f < 16; f++) tmp[f] = f2bf(src[f]);
  const short8* tv = (const short8*)tmp;
  *(short8*)&z0g[(long)r * 1024] = tv[0];
  *(short8*)&z0g[(long)r * 1024 + 8] = tv[1];
  *(short8*)&z0c[(long)r * 1024] = tv[0];
  *(short8*)&z0c[(long)r * 1024 + 8] = tv[1];
  #pragma unroll
  for (int f = 0; f < 16; f++) z0Tg[(long)f * 16384 + r] = tmp[f];
}

__global__ void zero_cols(u16* __restrict__ z, int ld, int c0) {  // zero 128 cols
  int idx = blockIdx.x * 256 + threadIdx.x;     // 16384*16
  int r = idx >> 4, s = idx & 15;
  short8 zz = {};
  *(short8*)&z[(long)r * ld + c0 + s * 8] = zz;
}

__global__ void cvtT(const float* __restrict__ Tf, const float* __restrict__ Tb,
                     u16* __restrict__ Tpow, u16* __restrict__ TfT, u16* __restrict__ TbT)
{
  int idx = blockIdx.x * 256 + threadIdx.x;     // 262144
  int i = idx >> 9, j = idx & 511;
  const float* s = blockIdx.y ? Tb : Tf;
  u16* d = Tpow + (blockIdx.y ? 3 : 0) * 262144;
  u16* dT = blockIdx.y ? TbT : TfT;
  u16 v = f2bf(s[idx]);
  d[idx] = v;
  dT[(long)j * 512 + i] = v;
}

__global__ __launch_bounds__(256) void gemm_pow(
    const u16* __restrict__ A0, const u16* __restrict__ B0, u16* __restrict__ C0,
    const u16* __restrict__ A1, const u16* __restrict__ B1, u16* __restrict__ C1)
{
  constexpr int BM = 64, BN = 64, BK = 32;
  __shared__ u16 sm[(BM + BN) * BK];
  const int tid = threadIdx.x, lane = tid & 63, wid = tid >> 6;
  const int wr = wid >> 1, wc = wid & 1;
  const int l15 = lane & 15, l4 = lane >> 4;
  const int m0 = blockIdx.x * BM, n0 = blockIdx.y * BN;
  const u16* A = blockIdx.z ? A1 : A0;
  const u16* Bt = blockIdx.z ? B1 : B0;
  u16* Cc = blockIdx.z ? C1 : C0;

  f32x4 acc[2][2] = {};
  for (int k0 = 0; k0 < 512; k0 += BK) {
    for (int s = tid; s < (BM + BN) * 4; s += 256) {
      const u16* gp;
      if (s < BM * 4) { int m = s >> 2, kc = s & 3; gp = A + (long)(m0 + m) * 512 + k0 + kc * 8; }
      else { int q = s - BM * 4; int n = q >> 2, kc = q & 3; gp = Bt + (long)(n0 + n) * 512 + k0 + kc * 8; }
      glds16(gp, sm + (s - lane) * 8);
    }
    __syncthreads();
    short8 af[2], bf[2];
    #pragma unroll
    for (int i = 0; i < 2; i++)
      af[i] = *(const short8*)&sm[(wr * 32 + i * 16 + l15) * BK + l4 * 8];
    #pragma unroll
    for (int j = 0; j < 2; j++)
      bf[j] = *(const short8*)&sm[BM * BK + (wc * 32 + j * 16 + l15) * BK + l4 * 8];
    #pragma unroll
    for (int i = 0; i < 2; i++)
      #pragma unroll
      for (int j = 0; j < 2; j++)
        acc[i][j] = __builtin_amdgcn_mfma_f32_16x16x32_bf16(af[i], bf[j], acc[i][j], 0, 0, 0);
    __syncthreads();
  }
  #pragma unroll
  for (int i = 0; i < 2; i++)
    #pragma unroll
    for (int j = 0; j < 2; j++) {
      int mb = m0 + wr * 32 + i * 16 + l4 * 4;
      int n = n0 + wc * 32 + j * 16 + l15;
      #pragma unroll
      for (int rr = 0; rr < 4; rr++)
        Cc[(long)(mb + rr) * 512 + n] = f2bf(acc[i][j][rr]);
    }
}

__global__ void wt_cvt(const float* __restrict__ W, u16* __restrict__ Wt,
                       int Ksrc, int Kpad, int Nout) {
  long idx = (long)blockIdx.x * 256 + threadIdx.x;
  if (idx >= (long)Nout * Kpad) return;
  int o = (int)(idx / Kpad), k = (int)(idx % Kpad);
  Wt[idx] = f2bf(k < Ksrc ? W[(long)k * Nout + o] : 0.f);
}

// ===========================================================================
extern "C" void kernel_launch(void* const* d_in, const int* in_sizes, int n_in,
                              void* d_out, int out_size, void* d_ws, size_t ws_size,
                              hipStream_t stream) {
  const float* x_seq = (const float*)d_in[0];
  const float* Tf  = (const float*)d_in[1];
  const float* Tb  = (const float*)d_in[2];
  const float* Wg0 = (const float*)d_in[3];
  const float* bg0 = (const float*)d_in[4];
  const float* Wc0 = (const float*)d_in[5];
  const float* bc0 = (const float*)d_in[6];
  const float* g0  = (const float*)d_in[7];
  const float* be0 = (const float*)d_in[8];
  const float* Wg1 = (const float*)d_in[9];
  const float* bg1 = (const float*)d_in[10];
  const float* Wc1 = (const float*)d_in[11];
  const float* bc1 = (const float*)d_in[12];
  const float* g1  = (const float*)d_in[13];
  const float* be1 = (const float*)d_in[14];

  constexpr int B = 32, T = 8;
  constexpr long M = 16384;

  char* p = (char*)d_ws;
  auto carve = [&](size_t bytes) { char* r = p; p += (bytes + 255) & ~(size_t)255; return r; };
  u16* z0g  = (u16*)carve(M * 1024 * 2);
  u16* z0c  = (u16*)carve(M * 1024 * 2);
  u16* z1g  = (u16*)carve(M * 1792 * 2);
  u16* z1c  = (u16*)carve(M * 1792 * 2);
  u16* z0Tg = (u16*)carve(144L * M * 2);
  u16* z0Tc = (u16*)carve(128L * M * 2);
  u16* z1Tg = (u16*)carve(256L * M * 2);
  u16* z1Tc = (u16*)carve(128L * M * 2);
  float* ubuf = (float*)carve(M * 128 * 4);
  u16* Tpow = (u16*)carve(6L * 512 * 512 * 2);   // Tf,Tf2,Tf3,Tb,Tb2,Tb3
  u16* TfT  = (u16*)carve(512L * 512 * 2);
  u16* TbT  = (u16*)carve(512L * 512 * 2);
  u16* Wg0t = (u16*)carve(256L * 1024 * 2);
  u16* Wc0t = (u16*)carve(128L * 1024 * 2);
  u16* Wg1t = (u16*)carve(256L * 1792 * 2);
  u16* Wc1t = (u16*)carve(128L * 1792 * 2);

  float* h0 = (float*)d_out;
  float* h1 = h0 + M * 128;

  hipMemsetAsync(d_out, 0, (size_t)out_size * 4, stream);
  zero_cols<<<1024, 256, 0, stream>>>(z0g, 1024, 16);
  zero_cols<<<1024, 256, 0, stream>>>(z1g, 1792, 128);
  hipMemsetAsync(z0Tg + 16L * M, 0, 128L * M * 2, stream);
  hipMemsetAsync(z1Tg + 128L * M, 0, 128L * M * 2, stream);

  cvtT<<<dim3(1024, 2), 256, 0, stream>>>(Tf, Tb, Tpow, TfT, TbT);
  gemm_pow<<<dim3(8, 8, 2), 256, 0, stream>>>(
      Tpow, TfT, Tpow + 1L * 262144, Tpow + 3L * 262144, TbT, Tpow + 4L * 262144);
  gemm_pow<<<dim3(8, 8, 2), 256, 0, stream>>>(
      Tpow + 1L * 262144, TfT, Tpow + 2L * 262144, Tpow + 4L * 262144, TbT, Tpow + 5L * 262144);
  wt_cvt<<<(256 * 1024 + 255) / 256, 256, 0, stream>>>(Wg0, Wg0t, 1008, 1024, 256);
  wt_cvt<<<(128 * 1024 + 255) / 256, 256, 0, stream>>>(Wc0, Wc0t, 1008, 1024, 128);
  wt_cvt<<<(256 * 1792 + 255) / 256, 256, 0, stream>>>(Wg1, Wg1t, 1792, 1792, 256);
  wt_cvt<<<(128 * 1792 + 255) / 256, 256, 0, stream>>>(Wc1, Wc1t, 1792, 1792, 128);

  xk<<<64, 256, 0, stream>>>(x_seq, 0, z0g, z0c, z0Tg);   // x(t=0)

  for (int t = 0; t < T; t++) {
    // ======== layer 0 (C=144, Kpad=1024) ========
    gemm_diff<128, 48, 4, 1><<<dim3(4, 3, 6 * B), 256, 0, stream>>>(
        Tpow, z0Tg, z0g, 1024, 144, 0, z0c, 16);
    gemm_proj<64, 64><<<dim3(256, 4), 256, 0, stream>>>(
        z0g, 1024, Wg0t, 1024, bg0, h0, z0c, 1024, 16, z0Tc, ubuf);
    gemm_diff<128, 64, 2, 2><<<dim3(4, 2, 6 * B), 256, 0, stream>>>(
        Tpow, z0Tc, z0c, 1024, 144, 16, nullptr, 0);
    proj_cand_gru<<<512, 256, 0, stream>>>(
        z0c, z0c, 1024, Wc0t, 1024, bc0, ubuf, h0, g0, be0,
        z0g, 1024, 16, z1g, 1792, 0, z0Tg, 16, z1Tg, 0,
        nullptr, 0, nullptr, nullptr, nullptr);
    // ======== layer 1 (C=256, Kpad=1792) ========
    gemm_diff<128, 64, 2, 2><<<dim3(4, 4, 6 * B), 256, 0, stream>>>(
        Tpow, z1Tg, z1g, 1792, 256, 0, nullptr, 0);
    gemm_proj<64, 64><<<dim3(256, 4), 256, 0, stream>>>(
        z1g, 1792, Wg1t, 1792, bg1, h1, z1c, 1792, 128, z1Tc, ubuf);
    gemm_diff<128, 64, 2, 2><<<dim3(4, 2, 6 * B), 256, 0, stream>>>(
        Tpow, z1Tc, z1c, 1792, 256, 128, nullptr, 0);
    // cand proj: h0-diffused halves from z1g, r*h1 halves from z1c;
    // also stages x(t+1) for the next step.
    proj_cand_gru<<<512, 256, 0, stream>>>(
        z1g, z1c, 1792, Wc1t, 1792, bc1, ubuf, h1, g1, be1,
        z1g, 1792, 128, nullptr, 0, 0, z1Tg, 128, nullptr, 0,
        (t < T - 1) ? x_seq : nullptr, t + 1, z0g, z0c, z0Tg);
  }
}

// Round 10
// 1485.806 us; speedup vs baseline: 1.1566x; 1.0653x over previous
//
#include <hip/hip_runtime.h>
#include <hip/hip_bf16.h>
#include <math.h>

typedef unsigned short u16;
typedef __attribute__((ext_vector_type(8))) short short8;
typedef __attribute__((ext_vector_type(4))) float f32x4;

__device__ __forceinline__ u16 f2bf(float f) {
  union { float f; unsigned u; } v; v.f = f;
  unsigned r = v.u + 0x7fffu + ((v.u >> 16) & 1u);
  return (u16)(r >> 16);
}

// async global->LDS, 16B/lane. LDS dest is wave-uniform base; HW adds lane*16.
__device__ __forceinline__ void glds16(const u16* g, u16* l) {
  __builtin_amdgcn_global_load_lds(
      (const __attribute__((address_space(1))) void*)g,
      (__attribute__((address_space(3))) void*)l, 16, 0, 0);
}

// Counted-vmcnt barrier (T4): wait until only N VMEM ops remain in flight
// (the prefetch), then block-barrier. Compiler fences pin LDS reads below.
template<int N> __device__ __forceinline__ void kbar() {
  asm volatile("s_waitcnt vmcnt(%0)" :: "n"(N) : "memory");
  __builtin_amdgcn_s_barrier();
  asm volatile("" ::: "memory");
}
// Plain barrier (no drain): protects buffer reuse.
__device__ __forceinline__ void bar2() {
  asm volatile("" ::: "memory");
  __builtin_amdgcn_s_barrier();
  asm volatile("" ::: "memory");
}

// ===========================================================================
// Diffusion, batch-paired: each block computes 2 batches sharing the A-tile
// (Tpow[tc]) — A staged once, two B windows (adjacent 512-chunks of zT rows).
// out[((b0+q)*512+node)*ldz + (1+tc)*C + coff0 + ch] = sum_k T[node][k]*zT[ch][(b0+q)*512+k]
// grid.z = (B/2)*6: b0 = 2*(z/6), tc = z%6. Dual-write ch<Fdual into zdual.
// BK=64, swizzled staging; 2-phase prefetch with counted vmcnt.
// ===========================================================================
template<int BM, int BN, int WR, int WC>
__global__ __launch_bounds__(256, 2) void gemm_diff(
    const u16* __restrict__ Tpow, const u16* __restrict__ zT,
    u16* __restrict__ zout, int ldz, int C, int coff0,
    u16* __restrict__ zdual, int Fdual)
{
  constexpr int BK = 64;
  constexpr int FM = BM / (WR * 16), FN = BN / (WC * 16);
  constexpr int SLOTS = (BM + 2 * BN) * 8;   // 16B slots per K-tile
  constexpr int NS = (SLOTS + 255) / 256;
  constexpr int VMIN = SLOTS / 256;          // safe floor for ragged shapes
  constexpr int HALF = (BM + 2 * BN) * BK;   // u16 per LDS buffer
  __shared__ u16 sm[2 * HALF];
  const int tid = threadIdx.x, lane = tid & 63, wid = tid >> 6;
  const int wr = wid / WC, wc = wid % WC;
  const int l15 = lane & 15, l4 = lane >> 4;
  const int m0 = blockIdx.x * BM;
  const int y0 = blockIdx.y * BN;
  const int b0 = (blockIdx.z / 6) * 2, tc = blockIdx.z % 6;
  const u16* A = Tpow + (long)tc * 262144;
  const int lb = (tid - lane) * 8;           // wave-uniform LDS dest (u16 units)

  const u16* gp[NS];
  #pragma unroll
  for (int i = 0; i < NS; i++) {
    int s = tid + i * 256;
    if (s < BM * 8) {
      int row = s >> 3, kc = s & 7;
      gp[i] = A + (long)(m0 + row) * 512 + (kc ^ (row & 7)) * 8;
    } else {
      int s2 = s - BM * 8;
      int q = s2 / (BN * 8), n = (s2 % (BN * 8)) >> 3, kc = s2 & 7;
      gp[i] = zT + (long)(y0 + n) * 16384 + (b0 + q) * 512 + (kc ^ (n & 7)) * 8;
    }
  }

  auto stage = [&](int buf) {
    u16* base = sm + buf * HALF + lb;
    #pragma unroll
    for (int i = 0; i < NS; i++) {
      if (i * 256 + 256 <= SLOTS || tid < SLOTS - i * 256)
        glds16(gp[i], base + i * 2048);
    }
    #pragma unroll
    for (int i = 0; i < NS; i++) gp[i] += BK;
  };

  f32x4 acc[2][FM][FN] = {};
  auto compute = [&](int buf) {
    const u16* smc = sm + buf * HALF;
    #pragma unroll
    for (int kk = 0; kk < 2; kk++) {
      short8 af[FM], bf[2][FN];
      #pragma unroll
      for (int i = 0; i < FM; i++) {
        int ar = wr * FM * 16 + i * 16 + l15;
        af[i] = *(const short8*)&smc[ar * BK + (((kk * 4 + l4) ^ (ar & 7)) << 3)];
      }
      #pragma unroll
      for (int q = 0; q < 2; q++)
        #pragma unroll
        for (int j = 0; j < FN; j++) {
          int br = wc * FN * 16 + j * 16 + l15;
          bf[q][j] = *(const short8*)&smc[BM * BK + q * BN * BK + br * BK +
                                          (((kk * 4 + l4) ^ (br & 7)) << 3)];
        }
      #pragma unroll
      for (int q = 0; q < 2; q++)
        #pragma unroll
        for (int i = 0; i < FM; i++)
          #pragma unroll
          for (int j = 0; j < FN; j++)
            acc[q][i][j] = __builtin_amdgcn_mfma_f32_16x16x32_bf16(af[i], bf[q][j], acc[q][i][j], 0, 0, 0);
    }
  };

  stage(0);
  int cur = 0;
  for (int t = 0; t < 7; t++) {              // NT = 512/64 = 8
    stage(cur ^ 1);
    kbar<VMIN>();                            // cur's loads done; prefetch in flight
    compute(cur);
    bar2();                                  // all waves done reading cur
    cur ^= 1;
  }
  kbar<0>();                                 // drain last tile
  compute(cur);

  const int tC = (1 + tc) * C;
  #pragma unroll
  for (int q = 0; q < 2; q++) {
    #pragma unroll
    for (int i = 0; i < FM; i++) {
      #pragma unroll
      for (int j = 0; j < FN; j++) {
        int node = m0 + wr * FM * 16 + i * 16 + l4 * 4;
        int ch = y0 + wc * FN * 16 + j * 16 + l15;
        #pragma unroll
        for (int rr = 0; rr < 4; rr++) {
          u16 v = f2bf(acc[q][i][j][rr]);
          long r = (long)(b0 + q) * 512 + node + rr;
          zout[r * ldz + tC + coff0 + ch] = v;
          if (Fdual && ch < Fdual) zdual[r * ldz + tC + ch] = v;
        }
      }
    }
  }
}

// ===========================================================================
// Gates projection (giant-M): out(16384,256) = sigmoid(z @ W^T + b)
// n<128 -> rh=sig*hst -> zc[r*ldzc+Foff+n] + zTc[n*16384+r]; n>=128 -> ubuf.
// ===========================================================================
template<int BM, int BN>
__global__ __launch_bounds__(256) void gemm_proj(
    const u16* __restrict__ Az, int ldA,
    const u16* __restrict__ W, int K,
    const float* __restrict__ bias,
    const float* __restrict__ hst,
    u16* __restrict__ zc, int ldzc, int Foff,
    u16* __restrict__ zTc,
    float* __restrict__ outbuf)
{
  constexpr int BK = 64;
  constexpr int FM = BM / 32, FN = BN / 32;   // 2x2 waves
  constexpr int NSA = BM / 32, NSB = BN / 32;
  constexpr int VMIN = NSA + NSB;
  constexpr int HALF = (BM + BN) * BK;
  __shared__ u16 sm[2 * HALF];
  const int tid = threadIdx.x, lane = tid & 63, wid = tid >> 6;
  const int wr = wid >> 1, wc = wid & 1;
  const int l15 = lane & 15, l4 = lane >> 4;
  const int m0 = blockIdx.x * BM;
  const int n0 = blockIdx.y * BN;
  const int lb = (tid - lane) * 8;

  const u16* ap[NSA];
  const u16* wp[NSB];
  #pragma unroll
  for (int i = 0; i < NSA; i++) {
    int s = tid + i * 256;
    int row = s >> 3, kc = s & 7;
    int kcg = kc ^ (row & 7);
    ap[i] = Az + (long)(m0 + row) * ldA + kcg * 8;
  }
  #pragma unroll
  for (int i = 0; i < NSB; i++) {
    int s = tid + (NSA + i) * 256;
    int row = s >> 3, kc = s & 7;
    int kcg = kc ^ (row & 7);
    wp[i] = W + (long)(n0 + row - BM) * K + kcg * 8;
  }

  auto stage = [&](int buf) {
    u16* base = sm + buf * HALF + lb;
    #pragma unroll
    for (int i = 0; i < NSA; i++) { glds16(ap[i], base + i * 2048); ap[i] += BK; }
    #pragma unroll
    for (int i = 0; i < NSB; i++) { glds16(wp[i], base + (NSA + i) * 2048); wp[i] += BK; }
  };

  f32x4 acc[FM][FN] = {};
  auto compute = [&](int buf) {
    const u16* smc = sm + buf * HALF;
    #pragma unroll
    for (int kk = 0; kk < 2; kk++) {
      short8 af[FM], bf[FN];
      #pragma unroll
      for (int i = 0; i < FM; i++) {
        int ar = wr * FM * 16 + i * 16 + l15;
        af[i] = *(const short8*)&smc[ar * BK + (((kk * 4 + l4) ^ (ar & 7)) << 3)];
      }
      #pragma unroll
      for (int j = 0; j < FN; j++) {
        int br = wc * FN * 16 + j * 16 + l15;
        bf[j] = *(const short8*)&smc[BM * BK + br * BK + (((kk * 4 + l4) ^ (br & 7)) << 3)];
      }
      #pragma unroll
      for (int i = 0; i < FM; i++)
        #pragma unroll
        for (int j = 0; j < FN; j++)
          acc[i][j] = __builtin_amdgcn_mfma_f32_16x16x32_bf16(af[i], bf[j], acc[i][j], 0, 0, 0);
    }
  };

  stage(0);
  int cur = 0;
  const int NT = K >> 6;
  for (int t = 1; t < NT; t++) {
    stage(cur ^ 1);
    kbar<VMIN>();
    compute(cur);
    bar2();
    cur ^= 1;
  }
  kbar<0>();
  compute(cur);

  #pragma unroll
  for (int i = 0; i < FM; i++) {
    #pragma unroll
    for (int j = 0; j < FN; j++) {
      int mb = m0 + wr * FM * 16 + i * 16 + l4 * 4;
      int n = n0 + wc * FN * 16 + j * 16 + l15;
      #pragma unroll
      for (int rr = 0; rr < 4; rr++) {
        float v = acc[i][j][rr] + bias[n];
        long r = mb + rr;
        float g = 1.f / (1.f + expf(-v));
        if (n < 128) {
          float rh = g * hst[r * 128 + n];
          u16 hv = f2bf(rh);
          zc[r * ldzc + Foff + n] = hv;
          zTc[(long)n * 16384 + r] = hv;
        } else {
          outbuf[r * 128 + (n - 128)] = g;
        }
      }
    }
  }
}

// ===========================================================================
// Fused candidate projection + GRU update + LayerNorm + fan-out.
// c = tanh(z @ Wc^T + b); hn = (1-u)h + u*c; h = LN(hn)*gamma+beta.
// BM=32 rows/block (within one batch), BN=128 = all H cols. grid (512).
// A K-chunks selected by bit7 of koff: Ag (bit7=0) / Ac (bit7=1).
// ===========================================================================
__global__ __launch_bounds__(256) void proj_cand_gru(
    const u16* __restrict__ Ag, const u16* __restrict__ Ac, int ldA,
    const u16* __restrict__ W, int K,
    const float* __restrict__ bias,
    const float* __restrict__ ub, float* __restrict__ h,
    const float* __restrict__ gamma, const float* __restrict__ beta,
    u16* __restrict__ rm0, int ld0, int co0,
    u16* __restrict__ rm1, int ld1, int co1,
    u16* __restrict__ cm0, int ro0,
    u16* __restrict__ cm1, int ro1,
    const float* __restrict__ xs, int tnext,
    u16* __restrict__ xz0g, u16* __restrict__ xz0c, u16* __restrict__ xz0T)
{
  constexpr int BM = 32, BN = 128, BK = 64;
  constexpr int FM = 2, FN = 2;              // 4 waves, wave grid 1x4
  constexpr int NSA = 1, NSB = 4;
  constexpr int HALF = (BM + BN) * BK;       // 10240 u16
  __shared__ u16 sm[2 * HALF];               // 40 KB (reused for LN)
  const int tid = threadIdx.x, lane = tid & 63, wid = tid >> 6;
  const int wc = wid;                         // 0..3
  const int l15 = lane & 15, l4 = lane >> 4;
  const int m0 = blockIdx.x * BM;
  const int lb = (tid - lane) * 8;

  unsigned aoff[NSA];
  const u16* wp[NSB];
  #pragma unroll
  for (int i = 0; i < NSA; i++) {
    int s = tid + i * 256;
    int row = s >> 3, kc = s & 7;
    int kcg = kc ^ (row & 7);
    aoff[i] = (unsigned)((m0 + row) * ldA + kcg * 8);
  }
  #pragma unroll
  for (int i = 0; i < NSB; i++) {
    int s = tid + (NSA + i) * 256;
    int row = (s >> 3) - BM, kc = s & 7;
    int kcg = kc ^ ((row + BM) & 7);
    wp[i] = W + (long)row * K + kcg * 8;
  }

  auto stage = [&](int buf, int koff) {
    u16* base = sm + buf * HALF + lb;
    const u16* ab = ((koff >> 7) & 1) ? Ac : Ag;
    #pragma unroll
    for (int i = 0; i < NSA; i++) glds16(ab + aoff[i] + koff, base + i * 2048);
    #pragma unroll
    for (int i = 0; i < NSB; i++) { glds16(wp[i], base + (NSA + i) * 2048); wp[i] += BK; }
  };

  f32x4 acc[FM][FN] = {};
  auto compute = [&](int buf) {
    const u16* smc = sm + buf * HALF;
    #pragma unroll
    for (int kk = 0; kk < 2; kk++) {
      short8 af[FM], bf[FN];
      #pragma unroll
      for (int i = 0; i < FM; i++) {
        int ar = i * 16 + l15;
        af[i] = *(const short8*)&smc[ar * BK + (((kk * 4 + l4) ^ (ar & 7)) << 3)];
      }
      #pragma unroll
      for (int j = 0; j < FN; j++) {
        int br = wc * 32 + j * 16 + l15;
        bf[j] = *(const short8*)&smc[BM * BK + br * BK + (((kk * 4 + l4) ^ (br & 7)) << 3)];
      }
      #pragma unroll
      for (int i = 0; i < FM; i++)
        #pragma unroll
        for (int j = 0; j < FN; j++)
          acc[i][j] = __builtin_amdgcn_mfma_f32_16x16x32_bf16(af[i], bf[j], acc[i][j], 0, 0, 0);
    }
  };

  stage(0, 0);
  int cur = 0;
  const int NT = K >> 6;
  for (int t = 1; t < NT; t++) {
    stage(cur ^ 1, t * 64);
    kbar<5>();                               // NSA+NSB = 5
    compute(cur);
    bar2();
    cur ^= 1;
  }
  kbar<0>();
  compute(cur);
  __syncthreads();                            // all waves done reading sm

  // GRU update into LDS (reuse sm as float hs[32][132])
  float* hs = (float*)sm;
  #pragma unroll
  for (int i = 0; i < FM; i++) {
    #pragma unroll
    for (int j = 0; j < FN; j++) {
      #pragma unroll
      for (int rr = 0; rr < 4; rr++) {
        int lrow = i * 16 + l4 * 4 + rr;
        int n = wc * 32 + j * 16 + l15;
        long r = m0 + lrow;
        float c = tanhf(acc[i][j][rr] + bias[n]);
        float u = ub[r * 128 + n];
        float hold = h[r * 128 + n];
        hs[lrow * 132 + n] = (1.f - u) * hold + u * c;
      }
    }
  }
  __syncthreads();

  // LayerNorm: 8 threads/row, 16 cols each
  {
    int row = tid >> 3, g = tid & 7;
    float s = 0.f, s2 = 0.f;
    #pragma unroll
    for (int k = 0; k < 16; k++) {
      float v = hs[row * 132 + g + 8 * k];
      s += v; s2 += v * v;
    }
    s += __shfl_xor(s, 1); s2 += __shfl_xor(s2, 1);
    s += __shfl_xor(s, 2); s2 += __shfl_xor(s2, 2);
    s += __shfl_xor(s, 4); s2 += __shfl_xor(s2, 4);
    float mu = s * (1.f / 128.f);
    float var = s2 * (1.f / 128.f) - mu * mu;
    float rs = rsqrtf(var + 1e-5f);
    long rb = (long)(m0 + row) * 128;
    #pragma unroll
    for (int k = 0; k < 16; k++) {
      int c = g + 8 * k;
      float v = (hs[row * 132 + c] - mu) * rs * gamma[c] + beta[c];
      h[rb + c] = v;
      hs[row * 132 + c] = v;
    }
  }
  __syncthreads();

  // row-major fan-out
  #pragma unroll
  for (int i = 0; i < 16; i++) {
    int idx = tid + i * 256;
    int row = idx >> 7, c = idx & 127;
    u16 v = f2bf(hs[row * 132 + c]);
    long r = m0 + row;
    rm0[r * ld0 + co0 + c] = v;
    if (rm1) rm1[r * ld1 + co1 + c] = v;
  }
  // ch-major fan-out
  {
    const int c2 = tid >> 1, half = tid & 1;
    u16 tmp[16];
    #pragma unroll
    for (int i = 0; i < 16; i++) tmp[i] = f2bf(hs[(half * 16 + i) * 132 + c2]);
    const short8* tv = (const short8*)tmp;
    long off = (long)(ro0 + c2) * 16384 + m0 + half * 16;
    *(short8*)&cm0[off] = tv[0];
    *(short8*)&cm0[off + 8] = tv[1];
    if (cm1) {
      long o2 = (long)(ro1 + c2) * 16384 + m0 + half * 16;
      *(short8*)&cm1[o2] = tv[0];
      *(short8*)&cm1[o2 + 8] = tv[1];
    }
  }
  // next-step x staging
  if (xs) {
    for (int e = tid; e < 512; e += 256) {
      int lrow = e >> 4, f = e & 15;
      long r = m0 + lrow;
      int b = (int)(r >> 9), n = (int)(r & 511);
      u16 v = f2bf(xs[(((long)b * 8 + tnext) * 512 + n) * 16 + f]);
      xz0g[r * 1024 + f] = v;
      xz0c[r * 1024 + f] = v;
      xz0T[(long)f * 16384 + r] = v;
    }
  }
}

// ===========================================================================
// small helpers
// ===========================================================================
__global__ __launch_bounds__(256) void xk(
    const float* __restrict__ xs, int t,
    u16* __restrict__ z0g, u16* __restrict__ z0c, u16* __restrict__ z0Tg)
{
  int r = blockIdx.x * 256 + threadIdx.x;       // 0..16383 = b*512+n
  int b = r >> 9, n = r & 511;
  const float* src = xs + (((long)b * 8 + t) * 512 + n) * 16;
  u16 tmp[16];
  #pragma unroll
  for (int f = 0; f < 16; f++) tmp[f] = f2bf(src[f]);
  const short8* tv = (const short8*)tmp;
  *(short8*)&z0g[(long)r * 1024] = tv[0];
  *(short8*)&z0g[(long)r * 1024 + 8] = tv[1];
  *(short8*)&z0c[(long)r * 1024] = tv[0];
  *(short8*)&z0c[(long)r * 1024 + 8] = tv[1];
  #pragma unroll
  for (int f = 0; f < 16; f++) z0Tg[(long)f * 16384 + r] = tmp[f];
}

__global__ void cvtT(const float* __restrict__ Tf, const float* __restrict__ Tb,
                     u16* __restrict__ Tpow, u16* __restrict__ TfT, u16* __restrict__ TbT)
{
  int idx = blockIdx.x * 256 + threadIdx.x;     // 262144
  int i = idx >> 9, j = idx & 511;
  const float* s = blockIdx.y ? Tb : Tf;
  u16* d = Tpow + (blockIdx.y ? 3 : 0) * 262144;
  u16* dT = blockIdx.y ? TbT : TfT;
  u16 v = f2bf(s[idx]);
  d[idx] = v;
  dT[(long)j * 512 + i] = v;
}

__global__ __launch_bounds__(256) void gemm_pow(
    const u16* __restrict__ A0, const u16* __restrict__ B0, u16* __restrict__ C0,
    const u16* __restrict__ A1, const u16* __restrict__ B1, u16* __restrict__ C1)
{
  constexpr int BM = 64, BN = 64, BK = 32;
  __shared__ u16 sm[(BM + BN) * BK];
  const int tid = threadIdx.x, lane = tid & 63, wid = tid >> 6;
  const int wr = wid >> 1, wc = wid & 1;
  const int l15 = lane & 15, l4 = lane >> 4;
  const int m0 = blockIdx.x * BM, n0 = blockIdx.y * BN;
  const u16* A = blockIdx.z ? A1 : A0;
  const u16* Bt = blockIdx.z ? B1 : B0;
  u16* Cc = blockIdx.z ? C1 : C0;

  f32x4 acc[2][2] = {};
  for (int k0 = 0; k0 < 512; k0 += BK) {
    for (int s = tid; s < (BM + BN) * 4; s += 256) {
      const u16* gp;
      if (s < BM * 4) { int m = s >> 2, kc = s & 3; gp = A + (long)(m0 + m) * 512 + k0 + kc * 8; }
      else { int q = s - BM * 4; int n = q >> 2, kc = q & 3; gp = Bt + (long)(n0 + n) * 512 + k0 + kc * 8; }
      glds16(gp, sm + (s - lane) * 8);
    }
    __syncthreads();
    short8 af[2], bf[2];
    #pragma unroll
    for (int i = 0; i < 2; i++)
      af[i] = *(const short8*)&sm[(wr * 32 + i * 16 + l15) * BK + l4 * 8];
    #pragma unroll
    for (int j = 0; j < 2; j++)
      bf[j] = *(const short8*)&sm[BM * BK + (wc * 32 + j * 16 + l15) * BK + l4 * 8];
    #pragma unroll
    for (int i = 0; i < 2; i++)
      #pragma unroll
      for (int j = 0; j < 2; j++)
        acc[i][j] = __builtin_amdgcn_mfma_f32_16x16x32_bf16(af[i], bf[j], acc[i][j], 0, 0, 0);
    __syncthreads();
  }
  #pragma unroll
  for (int i = 0; i < 2; i++)
    #pragma unroll
    for (int j = 0; j < 2; j++) {
      int mb = m0 + wr * 32 + i * 16 + l4 * 4;
      int n = n0 + wc * 32 + j * 16 + l15;
      #pragma unroll
      for (int rr = 0; rr < 4; rr++)
        Cc[(long)(mb + rr) * 512 + n] = f2bf(acc[i][j][rr]);
    }
}

__global__ void wt_cvt(const float* __restrict__ W, u16* __restrict__ Wt,
                       int Ksrc, int Kpad, int Nout) {
  long idx = (long)blockIdx.x * 256 + threadIdx.x;
  if (idx >= (long)Nout * Kpad) return;
  int o = (int)(idx / Kpad), k = (int)(idx % Kpad);
  Wt[idx] = f2bf(k < Ksrc ? W[(long)k * Nout + o] : 0.f);
}

// ===========================================================================
extern "C" void kernel_launch(void* const* d_in, const int* in_sizes, int n_in,
                              void* d_out, int out_size, void* d_ws, size_t ws_size,
                              hipStream_t stream) {
  const float* x_seq = (const float*)d_in[0];
  const float* Tf  = (const float*)d_in[1];
  const float* Tb  = (const float*)d_in[2];
  const float* Wg0 = (const float*)d_in[3];
  const float* bg0 = (const float*)d_in[4];
  const float* Wc0 = (const float*)d_in[5];
  const float* bc0 = (const float*)d_in[6];
  const float* g0  = (const float*)d_in[7];
  const float* be0 = (const float*)d_in[8];
  const float* Wg1 = (const float*)d_in[9];
  const float* bg1 = (const float*)d_in[10];
  const float* Wc1 = (const float*)d_in[11];
  const float* bc1 = (const float*)d_in[12];
  const float* g1  = (const float*)d_in[13];
  const float* be1 = (const float*)d_in[14];

  constexpr int B = 32, T = 8;
  constexpr long M = 16384;

  char* p = (char*)d_ws;
  auto carve = [&](size_t bytes) { char* r = p; p += (bytes + 255) & ~(size_t)255; return r; };
  u16* z0g  = (u16*)carve(M * 1024 * 2);
  u16* z0c  = (u16*)carve(M * 1024 * 2);
  u16* z1g  = (u16*)carve(M * 1792 * 2);
  u16* z1c  = (u16*)carve(M * 1792 * 2);
  u16* z0Tg = (u16*)carve(144L * M * 2);
  u16* z0Tc = (u16*)carve(128L * M * 2);
  u16* z1Tg = (u16*)carve(256L * M * 2);
  u16* z1Tc = (u16*)carve(128L * M * 2);
  float* ubuf = (float*)carve(M * 128 * 4);
  u16* Tpow = (u16*)carve(6L * 512 * 512 * 2);   // Tf,Tf2,Tf3,Tb,Tb2,Tb3
  u16* TfT  = (u16*)carve(512L * 512 * 2);
  u16* TbT  = (u16*)carve(512L * 512 * 2);
  u16* Wg0t = (u16*)carve(256L * 1024 * 2);
  u16* Wc0t = (u16*)carve(128L * 1024 * 2);
  u16* Wg1t = (u16*)carve(256L * 1792 * 2);
  u16* Wc1t = (u16*)carve(128L * 1792 * 2);

  float* h0 = (float*)d_out;
  float* h1 = h0 + M * 128;

  hipMemsetAsync(d_out, 0, (size_t)out_size * 4, stream);
  // zero all z buffers (contiguous carve region): enables the t=0 h-diffusion
  // skip (h=0 -> diffused h-terms = 0, pre-zeroed instead of computed).
  hipMemsetAsync(z0g, 0, (size_t)((char*)(z1c + M * 1792) - (char*)z0g), stream);
  hipMemsetAsync(z0Tg + 16L * M, 0, 128L * M * 2, stream);
  hipMemsetAsync(z1Tg + 128L * M, 0, 128L * M * 2, stream);

  cvtT<<<dim3(1024, 2), 256, 0, stream>>>(Tf, Tb, Tpow, TfT, TbT);
  gemm_pow<<<dim3(8, 8, 2), 256, 0, stream>>>(
      Tpow, TfT, Tpow + 1L * 262144, Tpow + 3L * 262144, TbT, Tpow + 4L * 262144);
  gemm_pow<<<dim3(8, 8, 2), 256, 0, stream>>>(
      Tpow + 1L * 262144, TfT, Tpow + 2L * 262144, Tpow + 4L * 262144, TbT, Tpow + 5L * 262144);
  wt_cvt<<<(256 * 1024 + 255) / 256, 256, 0, stream>>>(Wg0, Wg0t, 1008, 1024, 256);
  wt_cvt<<<(128 * 1024 + 255) / 256, 256, 0, stream>>>(Wc0, Wc0t, 1008, 1024, 128);
  wt_cvt<<<(256 * 1792 + 255) / 256, 256, 0, stream>>>(Wg1, Wg1t, 1792, 1792, 256);
  wt_cvt<<<(128 * 1792 + 255) / 256, 256, 0, stream>>>(Wc1, Wc1t, 1792, 1792, 128);

  xk<<<64, 256, 0, stream>>>(x_seq, 0, z0g, z0c, z0Tg);   // x(t=0)

  for (int t = 0; t < T; t++) {
    // ======== layer 0 (C=144, Kpad=1024) ========
    if (t == 0) {
      // h=0: only x-part (16 ch) needs diffusion; h-terms pre-zeroed
      gemm_diff<128, 16, 4, 1><<<dim3(4, 1, 96), 256, 0, stream>>>(
          Tpow, z0Tg, z0g, 1024, 144, 0, z0c, 16);
    } else {
      gemm_diff<128, 48, 4, 1><<<dim3(4, 3, 96), 256, 0, stream>>>(
          Tpow, z0Tg, z0g, 1024, 144, 0, z0c, 16);
    }
    gemm_proj<64, 64><<<dim3(256, 4), 256, 0, stream>>>(
        z0g, 1024, Wg0t, 1024, bg0, h0, z0c, 1024, 16, z0Tc, ubuf);
    if (t > 0)  // t=0: r*h = 0, diffused terms pre-zeroed
      gemm_diff<128, 64, 2, 2><<<dim3(4, 2, 96), 256, 0, stream>>>(
          Tpow, z0Tc, z0c, 1024, 144, 16, nullptr, 0);
    proj_cand_gru<<<512, 256, 0, stream>>>(
        z0c, z0c, 1024, Wc0t, 1024, bc0, ubuf, h0, g0, be0,
        z0g, 1024, 16, z1g, 1792, 0, z0Tg, 16, z1Tg, 0,
        nullptr, 0, nullptr, nullptr, nullptr);
    // ======== layer 1 (C=256, Kpad=1792) ========
    // t=0: h1=0 -> only h0-half (cols 0..128) needs diffusion
    gemm_diff<128, 64, 2, 2><<<dim3(4, (t == 0) ? 2 : 4, 96), 256, 0, stream>>>(
        Tpow, z1Tg, z1g, 1792, 256, 0, nullptr, 0);
    gemm_proj<64, 64><<<dim3(256, 4), 256, 0, stream>>>(
        z1g, 1792, Wg1t, 1792, bg1, h1, z1c, 1792, 128, z1Tc, ubuf);
    if (t > 0)  // t=0: r*h1 = 0, diffused terms pre-zeroed
      gemm_diff<128, 64, 2, 2><<<dim3(4, 2, 96), 256, 0, stream>>>(
          Tpow, z1Tc, z1c, 1792, 256, 128, nullptr, 0);
    // cand proj: h0-diffused halves from z1g, r*h1 halves from z1c;
    // also stages x(t+1) for the next step.
    proj_cand_gru<<<512, 256, 0, stream>>>(
        z1g, z1c, 1792, Wc1t, 1792, bc1, ubuf, h1, g1, be1,
        z1g, 1792, 128, nullptr, 0, 0, z1Tg, 128, nullptr, 0,
        (t < T - 1) ? x_seq : nullptr, t + 1, z0g, z0c, z0Tg);
  }
}